// Round 6
// baseline (821.183 us; speedup 1.0000x reference)
//
#include <hip/hip_runtime.h>
#include <hip/hip_bf16.h>

#define BB 8
#define CC 128
#define NN 4096
#define HH 4
#define FF 128
#define KK 16
#define HF 512   // H*F
#define CAP 120  // survivor capacity per query

typedef __attribute__((ext_vector_type(8))) short short8v;
typedef __attribute__((ext_vector_type(8))) unsigned short ushort8v;
typedef __attribute__((ext_vector_type(4))) float f32x4;

__device__ __forceinline__ float bf2f(unsigned int u) {
  return __uint_as_float(u << 16);
}

__device__ __forceinline__ unsigned short f2bf(float f) {
  unsigned int u = __float_as_uint(f);
  unsigned int lsb = (u >> 16) & 1u;
  u += 0x7fffu + lsb;                 // RTNE
  return (unsigned short)(u >> 16);
}

// ---------------------------------------------------------------------------
// x[b][c][n] -> xt[b][n][c] (f32), xhi[b][n][c] (bf16), hsq[b][n] = 0.5*|x|^2
__launch_bounds__(256)
__global__ void k_split(const float* __restrict__ x,
                        float* __restrict__ xt,
                        unsigned short* __restrict__ xhi,
                        float* __restrict__ hsq) {
  __shared__ float Ls[CC][65];
  int b = blockIdx.x >> 6, nb = blockIdx.x & 63;
  int n0 = nb * 64;
  int tid = threadIdx.x;
  const float* xb = x + (size_t)b * CC * NN;

  for (int i = tid; i < CC * 64; i += 256) {
    int c = i >> 6, nl = i & 63;
    Ls[c][nl] = xb[(size_t)c * NN + n0 + nl];
  }
  __syncthreads();

  int n = tid >> 2, part = tid & 3;     // 64 n x 4 parts (32 c each)
  int node = b * NN + n0 + n;
  float sum = 0.f;
#pragma unroll
  for (int g = 0; g < 4; ++g) {
    float v[8];
    ushort8v ph;
#pragma unroll
    for (int j = 0; j < 8; ++j) {
      int c = part * 32 + g * 8 + j;
      v[j] = Ls[c][n];
      ph[j] = f2bf(v[j]);
      sum += v[j] * v[j];
    }
    float4 f0 = {v[0], v[1], v[2], v[3]};
    float4 f1 = {v[4], v[5], v[6], v[7]};
    *(float4*)&xt[(size_t)node * CC + part * 32 + g * 8] = f0;
    *(float4*)&xt[(size_t)node * CC + part * 32 + g * 8 + 4] = f1;
    *(ushort8v*)&xhi[(size_t)node * CC + part * 32 + g * 8] = ph;
  }
  sum += __shfl_xor(sum, 1, 64);
  sum += __shfl_xor(sum, 2, 64);
  if (part == 0) hsq[node] = 0.5f * sum;
}

// ---------------------------------------------------------------------------
// Pack W[c][hf] f32 -> Whi/Wlo[hf][c] bf16
__global__ void k_wpack(const float* __restrict__ W,
                        unsigned short* __restrict__ Whi,
                        unsigned short* __restrict__ Wlo) {
  int i = blockIdx.x * 256 + threadIdx.x;   // over 512*128
  int hf = i >> 7, c = i & 127;
  float v = W[(size_t)c * HF + hf];
  unsigned short hb = f2bf(v);
  Whi[i] = hb;
  Wlo[i] = f2bf(v - bf2f(hb));
}

// ---------------------------------------------------------------------------
// Phase 1: per-half score histograms. Block = (batch, 64-query group, half).
// Wave sweeps 128 tiles for its 16 queries, binning scores into a packed LDS
// histogram (2 queries per u32 word, stride padded to 257 for bank spread).
// bin = clamp((bits(t+512) - 0x43800000) >> 16, 0, 255)  -- monotone in t.
// Output: part[half][q_global][bin] u8 (full overwrite, no pre-zero needed).
__launch_bounds__(256)
__global__ void k_hist(const unsigned short* __restrict__ xhi,
                       const float* __restrict__ hsq,
                       unsigned char* __restrict__ part) {
  __shared__ unsigned int hist[4][8][257];   // [wave][qpair][bin] ~32.9 KB
  int bx = blockIdx.x;
  int b = bx >> 7, rest = bx & 127;
  int qg = rest >> 1, ht = rest & 1;
  int w = threadIdx.x >> 6, lane = threadIdx.x & 63;
  int qcol = lane & 15, kg = lane >> 4;
  int base = b * NN;
  int q = base + qg * 64 + w * 16 + qcol;

  for (int i = threadIdx.x; i < 4 * 8 * 257; i += 256)
    ((unsigned int*)hist)[i] = 0;
  __syncthreads();

  const short8v* XH = (const short8v*)xhi;   // 16B granules: node*16 + ks*4 + kg
  short8v bh0 = XH[(size_t)q * 16 + kg];
  short8v bh1 = XH[(size_t)q * 16 + 4 + kg];
  short8v bh2 = XH[(size_t)q * 16 + 8 + kg];
  short8v bh3 = XH[(size_t)q * 16 + 12 + kg];

  unsigned int incr = (qcol & 1) ? 0x10000u : 1u;
  unsigned int* hrow = &hist[w][qcol >> 1][0];

#pragma unroll 1
  for (int lt = 0; lt < 128; ++lt) {
    int t = ht * 128 + lt;
    int mr = base + t * 16 + qcol;
    short8v ah0 = XH[(size_t)mr * 16 + kg];
    short8v ah1 = XH[(size_t)mr * 16 + 4 + kg];
    short8v ah2 = XH[(size_t)mr * 16 + 8 + kg];
    short8v ah3 = XH[(size_t)mr * 16 + 12 + kg];
    f32x4 acc = {0.f, 0.f, 0.f, 0.f};
    acc = __builtin_amdgcn_mfma_f32_16x16x32_bf16(ah0, bh0, acc, 0, 0, 0);
    acc = __builtin_amdgcn_mfma_f32_16x16x32_bf16(ah1, bh1, acc, 0, 0, 0);
    acc = __builtin_amdgcn_mfma_f32_16x16x32_bf16(ah2, bh2, acc, 0, 0, 0);
    acc = __builtin_amdgcn_mfma_f32_16x16x32_bf16(ah3, bh3, acc, 0, 0, 0);
    float4 hs = *(const float4*)&hsq[base + t * 16 + kg * 4];
    float hsa[4] = {hs.x, hs.y, hs.z, hs.w};
#pragma unroll
    for (int r = 0; r < 4; ++r) {
      float tv = acc[r] - hsa[r] + 512.0f;
      int bin = (int)((__float_as_uint(tv) - 0x43800000u)) >> 16;
      bin = bin < 0 ? 0 : (bin > 255 ? 255 : bin);
      atomicAdd(&hrow[bin], incr);
    }
  }
  __syncthreads();

  // write u8 partial: part[(ht*32768 + q_global)*256 + bin], 4 bins per u32
#pragma unroll 1
  for (int it = 0; it < 16; ++it) {
    int ql = w * 16 + it;
    unsigned int out = 0;
#pragma unroll
    for (int k = 0; k < 4; ++k) {
      unsigned int hv = hist[w][it >> 1][lane * 4 + k];
      unsigned int cv = (it & 1) ? (hv >> 16) : (hv & 0xffffu);
      cv = cv > 255u ? 255u : cv;
      out |= cv << (8 * k);
    }
    unsigned int* pw = (unsigned int*)(part +
        ((size_t)ht * 32768 + (size_t)(base + qg * 64 + ql)) * 256);
    pw[lane] = out;
  }
}

// ---------------------------------------------------------------------------
// Phase 2: per-query threshold. tau_bin = highest bin with cum>=16 from top;
// emit bit-space threshold for bin (tau_bin - 1)  [one-bin safety margin].
__global__ void k_tau(const unsigned char* __restrict__ part,
                      unsigned int* __restrict__ taub) {
  int g = blockIdx.x;             // query group = b*64+qg  (512 total)
  int q = threadIdx.x;            // 0..63
  int qglob = g * 64 + q;
  const unsigned char* p0 = part + (size_t)qglob * 256;
  const unsigned char* p1 = part + ((size_t)32768 + qglob) * 256;
  int cum = 0;
  int bin = 255;
  for (; bin >= 0; --bin) {
    cum += (int)p0[bin] + (int)p1[bin];
    if (cum >= KK) break;
  }
  int tu = bin - 1;
  if (tu < 0) tu = 0;
  taub[qglob] = 0x43800000u + ((unsigned int)tu << 16);
}

// ---------------------------------------------------------------------------
// Phase 3: collect survivors (score bits >= taub[q]) via global atomic append.
__launch_bounds__(256)
__global__ void k_collect(const unsigned short* __restrict__ xhi,
                          const float* __restrict__ hsq,
                          const unsigned int* __restrict__ taub,
                          unsigned int* __restrict__ cnt,
                          unsigned short* __restrict__ cand) {
  int bx = blockIdx.x;
  int b = bx >> 7, rest = bx & 127;
  int qg = rest >> 1, ht = rest & 1;
  int w = threadIdx.x >> 6, lane = threadIdx.x & 63;
  int qcol = lane & 15, kg = lane >> 4;
  int base = b * NN;
  int q = base + qg * 64 + w * 16 + qcol;

  const short8v* XH = (const short8v*)xhi;
  short8v bh0 = XH[(size_t)q * 16 + kg];
  short8v bh1 = XH[(size_t)q * 16 + 4 + kg];
  short8v bh2 = XH[(size_t)q * 16 + 8 + kg];
  short8v bh3 = XH[(size_t)q * 16 + 12 + kg];
  unsigned int ubase = taub[q];

#pragma unroll 1
  for (int lt = 0; lt < 128; ++lt) {
    int t = ht * 128 + lt;
    int mr = base + t * 16 + qcol;
    short8v ah0 = XH[(size_t)mr * 16 + kg];
    short8v ah1 = XH[(size_t)mr * 16 + 4 + kg];
    short8v ah2 = XH[(size_t)mr * 16 + 8 + kg];
    short8v ah3 = XH[(size_t)mr * 16 + 12 + kg];
    f32x4 acc = {0.f, 0.f, 0.f, 0.f};
    acc = __builtin_amdgcn_mfma_f32_16x16x32_bf16(ah0, bh0, acc, 0, 0, 0);
    acc = __builtin_amdgcn_mfma_f32_16x16x32_bf16(ah1, bh1, acc, 0, 0, 0);
    acc = __builtin_amdgcn_mfma_f32_16x16x32_bf16(ah2, bh2, acc, 0, 0, 0);
    acc = __builtin_amdgcn_mfma_f32_16x16x32_bf16(ah3, bh3, acc, 0, 0, 0);
    float4 hs = *(const float4*)&hsq[base + t * 16 + kg * 4];
    float hsa[4] = {hs.x, hs.y, hs.z, hs.w};
#pragma unroll
    for (int r = 0; r < 4; ++r) {
      float tv = acc[r] - hsa[r] + 512.0f;
      bool pass = __float_as_uint(tv) >= ubase;
      if (__any(pass)) {
        if (pass) {
          unsigned int pos = atomicAdd(&cnt[q], 1u);
          if (pos < CAP)
            cand[(size_t)q * CAP + pos] = (unsigned short)(t * 16 + kg * 4 + r);
        }
      }
    }
  }
}

// ---------------------------------------------------------------------------
// Exact f32 rerank of survivors -> top-16 (val desc, idx asc tie-break)
__launch_bounds__(256)
__global__ void k_rerank(const float* __restrict__ xt, const float* __restrict__ hsq,
                         const unsigned short* __restrict__ cand,
                         const unsigned int* __restrict__ cnt,
                         unsigned short* __restrict__ nbr) {
  int wq = blockIdx.x * 4 + (threadIdx.x >> 6);
  int lane = threadIdx.x & 63;
  int b = wq >> 12;
  int base = b * NN;
  int n = (int)cnt[wq]; if (n > CAP) n = CAP;
  const float* qr = xt + (size_t)wq * CC;

  float v0 = -3.4e38f; int i0 = 0x7fffffff;
  if (lane < n) {
    int c0 = cand[(size_t)wq * CAP + lane];
    const float* cr = xt + (size_t)(base + c0) * CC;
    float acc = 0.f;
#pragma unroll
    for (int c = 0; c < CC; c += 4) {
      float4 qa = *(const float4*)&qr[c];
      float4 ca = *(const float4*)&cr[c];
      acc = fmaf(qa.x, ca.x, acc);
      acc = fmaf(qa.y, ca.y, acc);
      acc = fmaf(qa.z, ca.z, acc);
      acc = fmaf(qa.w, ca.w, acc);
    }
    v0 = acc - hsq[base + c0];
    i0 = c0;
  }
  float v1 = -3.4e38f; int i1 = 0x7fffffff;
  if (n > 64) {
    if (lane + 64 < n) {
      int c1 = cand[(size_t)wq * CAP + 64 + lane];
      const float* cr = xt + (size_t)(base + c1) * CC;
      float acc = 0.f;
#pragma unroll
      for (int c = 0; c < CC; c += 4) {
        float4 qa = *(const float4*)&qr[c];
        float4 ca = *(const float4*)&cr[c];
        acc = fmaf(qa.x, ca.x, acc);
        acc = fmaf(qa.y, ca.y, acc);
        acc = fmaf(qa.z, ca.z, acc);
        acc = fmaf(qa.w, ca.w, acc);
      }
      v1 = acc - hsq[base + c1];
      i1 = c1;
    }
  }

  bool sw = (v1 > v0) || (v1 == v0 && i1 < i0);
  if (sw) {
    float tv = v0; v0 = v1; v1 = tv;
    int ti = i0; i0 = i1; i1 = ti;
  }
  unsigned short* o = nbr + (size_t)wq * KK;
  for (int s = 0; s < KK; ++s) {
    float wv = v0; int wi = i0;
#pragma unroll
    for (int off = 1; off < 64; off <<= 1) {
      float ov = __shfl_xor(wv, off, 64);
      int oi = __shfl_xor(wi, off, 64);
      bool take = (ov > wv) || (ov == wv && oi < wi);
      wv = take ? ov : wv;
      wi = take ? oi : wi;
    }
    if (lane == 0) o[s] = (unsigned short)wi;
    if (i0 == wi) {
      v0 = v1; i0 = i1;
      v1 = -3.4e38f; i1 = 0x7fffffff;
    }
  }
}

// ---------------------------------------------------------------------------
// h = xt . W via 3-term split-bf16 MFMA (xhi*Whi + xhi*Wlo + xlo*Whi), bf16 out
__launch_bounds__(256)
__global__ void k_h2(const float* __restrict__ xt,
                     const unsigned short* __restrict__ Whi,
                     const unsigned short* __restrict__ Wlo,
                     unsigned short* __restrict__ hout) {
  int w = threadIdx.x >> 6, lane = threadIdx.x & 63;
  int r16 = lane & 15, kg = lane >> 4;
  int nd0 = blockIdx.x * 64 + w * 16;
  const float* arow = xt + (size_t)(nd0 + r16) * CC;
  short8v ahi[4], alo[4];
#pragma unroll
  for (int ks = 0; ks < 4; ++ks) {
    float4 f0 = *(const float4*)&arow[ks * 32 + kg * 8];
    float4 f1 = *(const float4*)&arow[ks * 32 + kg * 8 + 4];
    float fv[8] = {f0.x, f0.y, f0.z, f0.w, f1.x, f1.y, f1.z, f1.w};
    short8v hh_, ll_;
#pragma unroll
    for (int j = 0; j < 8; ++j) {
      unsigned short hb = f2bf(fv[j]);
      hh_[j] = (short)hb;
      ll_[j] = (short)f2bf(fv[j] - bf2f(hb));
    }
    ahi[ks] = hh_; alo[ks] = ll_;
  }
  const short8v* WH = (const short8v*)Whi;   // granule: hf*16 + ks*4 + kg
  const short8v* WL = (const short8v*)Wlo;
#pragma unroll 1
  for (int ct = 0; ct < 32; ++ct) {
    int hf = ct * 16 + r16;
    f32x4 acc = {0.f, 0.f, 0.f, 0.f};
#pragma unroll
    for (int ks = 0; ks < 4; ++ks) {
      short8v bh = WH[(size_t)hf * 16 + ks * 4 + kg];
      short8v bl = WL[(size_t)hf * 16 + ks * 4 + kg];
      acc = __builtin_amdgcn_mfma_f32_16x16x32_bf16(ahi[ks], bh, acc, 0, 0, 0);
      acc = __builtin_amdgcn_mfma_f32_16x16x32_bf16(ahi[ks], bl, acc, 0, 0, 0);
      acc = __builtin_amdgcn_mfma_f32_16x16x32_bf16(alo[ks], bh, acc, 0, 0, 0);
    }
#pragma unroll
    for (int r = 0; r < 4; ++r)
      hout[(size_t)(nd0 + kg * 4 + r) * HF + hf] = f2bf(acc[r]);
  }
}

// ---------------------------------------------------------------------------
// a_src/a_dst[b][n][h] = sum_f h[b][n][h][f] * att_{src,dst}[h][f]
__global__ void k_att(const unsigned short* __restrict__ h,
                      const float* __restrict__ att_src, const float* __restrict__ att_dst,
                      float* __restrict__ a_src, float* __restrict__ a_dst) {
  int gid = blockIdx.x * 256 + threadIdx.x;
  int wid = gid >> 6;            // node index b*N+n
  int lane = threadIdx.x & 63;
  uint4 v = ((const uint4*)(h + (size_t)wid * HF))[lane];
  float hv[8];
  hv[0] = bf2f(v.x & 0xffff); hv[1] = bf2f(v.x >> 16);
  hv[2] = bf2f(v.y & 0xffff); hv[3] = bf2f(v.y >> 16);
  hv[4] = bf2f(v.z & 0xffff); hv[5] = bf2f(v.z >> 16);
  hv[6] = bf2f(v.w & 0xffff); hv[7] = bf2f(v.w >> 16);
  int base = lane * 8;
  float s = 0.f, d = 0.f;
#pragma unroll
  for (int i = 0; i < 8; ++i) {
    s += hv[i] * att_src[base + i];
    d += hv[i] * att_dst[base + i];
  }
#pragma unroll
  for (int off = 1; off < 16; off <<= 1) {
    s += __shfl_xor(s, off, 64);
    d += __shfl_xor(d, off, 64);
  }
  if ((lane & 15) == 0) {
    int hh = lane >> 4;
    a_src[wid * HH + hh] = s;
    a_dst[wid * HH + hh] = d;
  }
}

// ---------------------------------------------------------------------------
// gather + softmax(k=16) + weighted sum + head-mean + bias + transpose store
__launch_bounds__(256)
__global__ void k_out(const unsigned short* __restrict__ h,
                      const unsigned short* __restrict__ nbr,
                      const float* __restrict__ a_src, const float* __restrict__ a_dst,
                      const float* __restrict__ bias, float* __restrict__ out) {
  __shared__ float Ot[FF][17];
  int b = blockIdx.x >> 8, nb = blockIdx.x & 255;
  int w = threadIdx.x >> 6, lane = threadIdx.x & 63;
  int hh = lane >> 4, jj = lane & 15;

  for (int t = 0; t < 4; ++t) {
    int nl = w * 4 + t;
    int node = b * NN + nb * 16 + nl;
    int mj = nbr[node * KK + jj];

    float e = a_src[((size_t)b * NN + mj) * HH + hh] + a_dst[(size_t)node * HH + hh];
    e = e >= 0.f ? e : 0.2f * e;
    float m = e;
#pragma unroll
    for (int off = 1; off < 16; off <<= 1) m = fmaxf(m, __shfl_xor(m, off, 64));
    float p = expf(e - m);
    float sum = p;
#pragma unroll
    for (int off = 1; off < 16; off <<= 1) sum += __shfl_xor(sum, off, 64);
    float alpha = p / sum;

    float acc[8];
#pragma unroll
    for (int i = 0; i < 8; ++i) acc[i] = 0.f;

#pragma unroll
    for (int j = 0; j < 16; ++j) {
      float aj = __shfl(alpha, (hh << 4) | j, 64);
      int m2 = __shfl(mj, j, 64);
      uint4 v = ((const uint4*)(h + (size_t)(b * NN + m2) * HF))[lane];
      acc[0] += aj * bf2f(v.x & 0xffff); acc[1] += aj * bf2f(v.x >> 16);
      acc[2] += aj * bf2f(v.y & 0xffff); acc[3] += aj * bf2f(v.y >> 16);
      acc[4] += aj * bf2f(v.z & 0xffff); acc[5] += aj * bf2f(v.z >> 16);
      acc[6] += aj * bf2f(v.w & 0xffff); acc[7] += aj * bf2f(v.w >> 16);
    }

#pragma unroll
    for (int i = 0; i < 8; ++i) {
      acc[i] += __shfl_xor(acc[i], 16, 64);
      acc[i] += __shfl_xor(acc[i], 32, 64);
    }
    if (hh == 0) {
#pragma unroll
      for (int i = 0; i < 8; ++i) Ot[jj * 8 + i][nl] = acc[i] * 0.25f;
    }
  }
  __syncthreads();

#pragma unroll
  for (int it = 0; it < 8; ++it) {
    int idx = it * 256 + threadIdx.x;
    int f = idx >> 4, nl = idx & 15;
    out[((size_t)b * FF + f) * NN + nb * 16 + nl] = Ot[f][nl] + bias[f];
  }
}

// ---------------------------------------------------------------------------
extern "C" void kernel_launch(void* const* d_in, const int* in_sizes, int n_in,
                              void* d_out, int out_size, void* d_ws, size_t ws_size,
                              hipStream_t stream) {
  const float* x       = (const float*)d_in[0];
  const float* W       = (const float*)d_in[1];
  const float* att_src = (const float*)d_in[2];
  const float* att_dst = (const float*)d_in[3];
  const float* bias    = (const float*)d_in[4];

  char* ws = (char*)d_ws;
  // Lifetime-aliased layout; every size computed explicitly:
  //   [0        ,16777216): xt    f32 32768*128*4 = 16,777,216 — split..rerank,h2
  //   [16777216 ,25165824): xhi   bf16 32768*128*2 = 8,388,608 — split..collect
  //   [25165824 ,33030144): cand  u16 32768*120*2 = 7,864,320  — collect..rerank
  //   [33030144 ,49807360): part  u8 2*32768*256 = 16,777,216  — hist..tau  [FITS]
  //   [16777216 ,50331648): h     bf16 32768*512*2 = 33,554,432 — k_h2 AFTER rerank
  //   [50331648 ,51380224): nbr   u16 32768*16*2 = 1,048,576   — rerank..out
  //   [51380224 ,51511296): cnt   u32 131,072 (memset/launch)  — collect..rerank
  //   [51511296 ,51642368): taub  u32 131,072                  — tau..collect
  //   [51642368 ,51773440): hsq   f32 131,072                  — split..rerank
  //   [51773440 ,52297728): a_src f32 524,288 (aliased early by Whi/Wlo 2*262,144)
  //   [52297728 ,52822016): a_dst f32 524,288
  // total 52,822,016 B (= R4's passing envelope)
  float* xt            = (float*)ws;
  unsigned short* xhi  = (unsigned short*)(ws + 16777216);
  unsigned short* cand = (unsigned short*)(ws + 25165824);
  unsigned char* part  = (unsigned char*)(ws + 33030144);
  unsigned short* h    = (unsigned short*)(ws + 16777216);
  unsigned short* nbr  = (unsigned short*)(ws + 50331648);
  unsigned int* cnt    = (unsigned int*)(ws + 51380224);
  unsigned int* taub   = (unsigned int*)(ws + 51511296);
  float* hsq   = (float*)(ws + 51642368);
  float* a_src = (float*)(ws + 51773440);
  unsigned short* Whi  = (unsigned short*)(ws + 51773440);
  unsigned short* Wlo  = (unsigned short*)(ws + 51773440 + 131072);
  float* a_dst = (float*)(ws + 52297728);

  float* out = (float*)d_out;

  k_split  <<<BB * (NN / 64), 256, 0, stream>>>(x, xt, xhi, hsq);
  k_wpack  <<<HF * CC / 256, 256, 0, stream>>>(W, Whi, Wlo);
  k_hist   <<<BB * 64 * 2, 256, 0, stream>>>(xhi, hsq, part);
  k_tau    <<<BB * 64, 64, 0, stream>>>(part, taub);
  hipMemsetAsync(cnt, 0, 131072, stream);
  k_collect<<<BB * 64 * 2, 256, 0, stream>>>(xhi, hsq, taub, cnt, cand);
  k_rerank <<<BB * NN / 4, 256, 0, stream>>>(xt, hsq, cand, cnt, nbr);
  k_h2     <<<BB * NN / 64, 256, 0, stream>>>(xt, Whi, Wlo, h);
  k_att    <<<BB * NN / 4, 256, 0, stream>>>(h, att_src, att_dst, a_src, a_dst);
  k_out    <<<BB * (NN / 16), 256, 0, stream>>>(h, nbr, a_src, a_dst, bias, out);
}

// Round 8
// 740.430 us; speedup vs baseline: 1.1091x; 1.1091x over previous
//
#include <hip/hip_runtime.h>
#include <hip/hip_bf16.h>

#define BB 8
#define CC 128
#define NN 4096
#define HH 4
#define FF 128
#define KK 16
#define HF 512      // H*F
#define CAPH 128    // survivor capacity per query per half (stride 256 total)
#define WBUF 2048   // per-wave compaction buffer entries

typedef __attribute__((ext_vector_type(8))) short short8v;
typedef __attribute__((ext_vector_type(8))) unsigned short ushort8v;
typedef __attribute__((ext_vector_type(4))) float f32x4;

__device__ __forceinline__ float bf2f(unsigned int u) {
  return __uint_as_float(u << 16);
}

__device__ __forceinline__ unsigned short f2bf(float f) {
  unsigned int u = __float_as_uint(f);
  unsigned int lsb = (u >> 16) & 1u;
  u += 0x7fffu + lsb;                 // RTNE
  return (unsigned short)(u >> 16);
}

__device__ __forceinline__ unsigned int umin2(unsigned int a, unsigned int b) {
  return a < b ? a : b;
}
__device__ __forceinline__ unsigned int umin3(unsigned int a, unsigned int b, unsigned int c) {
  return umin2(umin2(a, b), c);
}

// ---------------------------------------------------------------------------
// x[b][c][n] -> xt[b][n][c] (f32), xhi[b][n][c] (bf16), hsq[b][n] = 0.5*|x|^2
__launch_bounds__(256)
__global__ void k_split(const float* __restrict__ x,
                        float* __restrict__ xt,
                        unsigned short* __restrict__ xhi,
                        float* __restrict__ hsq) {
  __shared__ float Ls[CC][65];
  int b = blockIdx.x >> 6, nb = blockIdx.x & 63;
  int n0 = nb * 64;
  int tid = threadIdx.x;
  const float* xb = x + (size_t)b * CC * NN;

  for (int i = tid; i < CC * 64; i += 256) {
    int c = i >> 6, nl = i & 63;
    Ls[c][nl] = xb[(size_t)c * NN + n0 + nl];
  }
  __syncthreads();

  int n = tid >> 2, part = tid & 3;     // 64 n x 4 parts (32 c each)
  int node = b * NN + n0 + n;
  float sum = 0.f;
#pragma unroll
  for (int g = 0; g < 4; ++g) {
    float v[8];
    ushort8v ph;
#pragma unroll
    for (int j = 0; j < 8; ++j) {
      int c = part * 32 + g * 8 + j;
      v[j] = Ls[c][n];
      ph[j] = f2bf(v[j]);
      sum += v[j] * v[j];
    }
    float4 f0 = {v[0], v[1], v[2], v[3]};
    float4 f1 = {v[4], v[5], v[6], v[7]};
    *(float4*)&xt[(size_t)node * CC + part * 32 + g * 8] = f0;
    *(float4*)&xt[(size_t)node * CC + part * 32 + g * 8 + 4] = f1;
    *(ushort8v*)&xhi[(size_t)node * CC + part * 32 + g * 8] = ph;
  }
  sum += __shfl_xor(sum, 1, 64);
  sum += __shfl_xor(sum, 2, 64);
  if (part == 0) hsq[node] = 0.5f * sum;
}

// ---------------------------------------------------------------------------
// Pack W[c][hf] f32 -> Whi/Wlo[hf][c] bf16
__global__ void k_wpack(const float* __restrict__ W,
                        unsigned short* __restrict__ Whi,
                        unsigned short* __restrict__ Wlo) {
  int i = blockIdx.x * 256 + threadIdx.x;   // over 512*128
  int hf = i >> 7, c = i & 127;
  float v = W[(size_t)c * HF + hf];
  unsigned short hb = f2bf(v);
  Whi[i] = hb;
  Wlo[i] = f2bf(v - bf2f(hb));
}

// ---------------------------------------------------------------------------
// tau scan: per-lane insert top-16 over candidates 0..1023 (subset, same for
// all queries -> L2-resident). Merge 4 lanes -> per-query 16th-best key;
// thr[q] = floor16(key) - 0.5 (covers subset order-stat bound + 2*eps + floor).
__launch_bounds__(256)
__global__ void k_tauscan(const unsigned short* __restrict__ xhi,
                          const float* __restrict__ hsq,
                          float* __restrict__ thr) {
  __shared__ unsigned int mv[4][16][64];   // 16 KB
  int b = blockIdx.x >> 6, qg = blockIdx.x & 63;
  int w = threadIdx.x >> 6, lane = threadIdx.x & 63;
  int qcol = lane & 15, kg = lane >> 4;
  int base = b * NN;
  int q = base + qg * 64 + w * 16 + qcol;

  const short8v* XH = (const short8v*)xhi;   // 16B granules: node*16 + ks*4 + kg
  short8v bh0 = XH[(size_t)q * 16 + kg];
  short8v bh1 = XH[(size_t)q * 16 + 4 + kg];
  short8v bh2 = XH[(size_t)q * 16 + 8 + kg];
  short8v bh3 = XH[(size_t)q * 16 + 12 + kg];

  unsigned int bd[16];

#pragma unroll
  for (int lt = 0; lt < 4; ++lt) {
    int mr = base + lt * 16 + qcol;
    short8v ah0 = XH[(size_t)mr * 16 + kg];
    short8v ah1 = XH[(size_t)mr * 16 + 4 + kg];
    short8v ah2 = XH[(size_t)mr * 16 + 8 + kg];
    short8v ah3 = XH[(size_t)mr * 16 + 12 + kg];
    f32x4 acc = {0.f, 0.f, 0.f, 0.f};
    acc = __builtin_amdgcn_mfma_f32_16x16x32_bf16(ah0, bh0, acc, 0, 0, 0);
    acc = __builtin_amdgcn_mfma_f32_16x16x32_bf16(ah1, bh1, acc, 0, 0, 0);
    acc = __builtin_amdgcn_mfma_f32_16x16x32_bf16(ah2, bh2, acc, 0, 0, 0);
    acc = __builtin_amdgcn_mfma_f32_16x16x32_bf16(ah3, bh3, acc, 0, 0, 0);
    float4 hs = *(const float4*)&hsq[base + lt * 16 + kg * 4];
    float hsa[4] = {hs.x, hs.y, hs.z, hs.w};
#pragma unroll
    for (int r = 0; r < 4; ++r) {
      float tv = acc[r] - hsa[r] + 512.0f;
      bd[lt * 4 + r] = (__float_as_uint(tv) & ~1023u) | (1023u - (unsigned)(lt * 4 + r));
    }
  }
  unsigned int m0 = umin3(bd[0], bd[1], bd[2]);
  m0 = umin3(m0, bd[3], bd[4]);
  m0 = umin3(m0, bd[5], bd[6]);
  m0 = umin2(m0, bd[7]);
  unsigned int m1 = umin3(bd[8], bd[9], bd[10]);
  m1 = umin3(m1, bd[11], bd[12]);
  m1 = umin3(m1, bd[13], bd[14]);
  m1 = umin2(m1, bd[15]);
  unsigned int worst = umin2(m0, m1);

#pragma unroll 1
  for (int lt = 4; lt < 64; ++lt) {
    int mr = base + lt * 16 + qcol;
    short8v ah0 = XH[(size_t)mr * 16 + kg];
    short8v ah1 = XH[(size_t)mr * 16 + 4 + kg];
    short8v ah2 = XH[(size_t)mr * 16 + 8 + kg];
    short8v ah3 = XH[(size_t)mr * 16 + 12 + kg];
    f32x4 acc = {0.f, 0.f, 0.f, 0.f};
    acc = __builtin_amdgcn_mfma_f32_16x16x32_bf16(ah0, bh0, acc, 0, 0, 0);
    acc = __builtin_amdgcn_mfma_f32_16x16x32_bf16(ah1, bh1, acc, 0, 0, 0);
    acc = __builtin_amdgcn_mfma_f32_16x16x32_bf16(ah2, bh2, acc, 0, 0, 0);
    acc = __builtin_amdgcn_mfma_f32_16x16x32_bf16(ah3, bh3, acc, 0, 0, 0);
    float4 hs = *(const float4*)&hsq[base + lt * 16 + kg * 4];
    float hsa[4] = {hs.x, hs.y, hs.z, hs.w};
#pragma unroll
    for (int r = 0; r < 4; ++r) {
      float tv = acc[r] - hsa[r] + 512.0f;
      unsigned int key = (__float_as_uint(tv) & ~1023u) | (1023u - (unsigned)(lt * 4 + r));
      if (key > worst) {
#pragma unroll
        for (int i = 0; i < 16; ++i) bd[i] = (bd[i] == worst) ? key : bd[i];
        unsigned int n0_ = umin3(bd[0], bd[1], bd[2]);
        n0_ = umin3(n0_, bd[3], bd[4]);
        n0_ = umin3(n0_, bd[5], bd[6]);
        n0_ = umin2(n0_, bd[7]);
        unsigned int n1_ = umin3(bd[8], bd[9], bd[10]);
        n1_ = umin3(n1_, bd[11], bd[12]);
        n1_ = umin3(n1_, bd[13], bd[14]);
        n1_ = umin2(n1_, bd[15]);
        worst = umin2(n0_, n1_);
      }
    }
  }

#pragma unroll
  for (int i = 0; i < 16; ++i) mv[w][qcol][kg * 16 + i] = bd[i];
  __syncthreads();

  if (lane < 16) {
    unsigned int tb[16];
#pragma unroll
    for (int i = 0; i < 16; ++i) tb[i] = mv[w][lane][i];
    unsigned int w0 = umin3(tb[0], tb[1], tb[2]);
    w0 = umin3(w0, tb[3], tb[4]);
    w0 = umin3(w0, tb[5], tb[6]);
    w0 = umin2(w0, tb[7]);
    unsigned int w1 = umin3(tb[8], tb[9], tb[10]);
    w1 = umin3(w1, tb[11], tb[12]);
    w1 = umin3(w1, tb[13], tb[14]);
    w1 = umin2(w1, tb[15]);
    unsigned int wst = umin2(w0, w1);
    for (int j = 16; j < 64; ++j) {
      unsigned int v = mv[w][lane][j];
      if (v > wst) {
        bool done = false;
#pragma unroll
        for (int i = 0; i < 16; ++i) {
          bool m = (!done) && (tb[i] == wst);
          done = done || m;
          tb[i] = m ? v : tb[i];
        }
        unsigned int a0 = umin3(tb[0], tb[1], tb[2]);
        a0 = umin3(a0, tb[3], tb[4]);
        a0 = umin3(a0, tb[5], tb[6]);
        a0 = umin2(a0, tb[7]);
        unsigned int a1 = umin3(tb[8], tb[9], tb[10]);
        a1 = umin3(a1, tb[11], tb[12]);
        a1 = umin3(a1, tb[13], tb[14]);
        a1 = umin2(a1, tb[15]);
        wst = umin2(a0, a1);
      }
    }
    thr[base + qg * 64 + w * 16 + lane] = __uint_as_float(wst & ~1023u) - 0.5f;
  }
}

// ---------------------------------------------------------------------------
// Collect survivors (tv >= thr[q]) via ballot-compaction into a per-wave LDS
// list (NO atomics in sweep), then bucket into per-(query,half) global lists.
// Caps: WBUF=2048/wave (46-sigma), CAPH=128/query-half (10-sigma) — unreachable.
__launch_bounds__(256)
__global__ void k_collect2(const unsigned short* __restrict__ xhi,
                           const float* __restrict__ hsq,
                           const float* __restrict__ thr,
                           unsigned short* __restrict__ cand,
                           unsigned short* __restrict__ qcnt) {
  __shared__ unsigned int buf[4][WBUF];   // 32 KB
  __shared__ unsigned int qc[4][16];
  int bx = blockIdx.x;
  int b = bx >> 7, rest = bx & 127;
  int qg = rest >> 1, ht = rest & 1;
  int w = threadIdx.x >> 6, lane = threadIdx.x & 63;
  int qcol = lane & 15, kg = lane >> 4;
  int base = b * NN;
  int q = base + qg * 64 + w * 16 + qcol;

  const short8v* XH = (const short8v*)xhi;
  short8v bh0 = XH[(size_t)q * 16 + kg];
  short8v bh1 = XH[(size_t)q * 16 + 4 + kg];
  short8v bh2 = XH[(size_t)q * 16 + 8 + kg];
  short8v bh3 = XH[(size_t)q * 16 + 12 + kg];
  float myThr = thr[q];
  if (lane < 16) qc[w][lane] = 0;

  int wbase = 0;
  unsigned long long ltmask = (1ull << lane) - 1ull;

#pragma unroll 1
  for (int lt = 0; lt < 128; ++lt) {
    int t = ht * 128 + lt;
    int mr = base + t * 16 + qcol;
    short8v ah0 = XH[(size_t)mr * 16 + kg];
    short8v ah1 = XH[(size_t)mr * 16 + 4 + kg];
    short8v ah2 = XH[(size_t)mr * 16 + 8 + kg];
    short8v ah3 = XH[(size_t)mr * 16 + 12 + kg];
    f32x4 acc = {0.f, 0.f, 0.f, 0.f};
    acc = __builtin_amdgcn_mfma_f32_16x16x32_bf16(ah0, bh0, acc, 0, 0, 0);
    acc = __builtin_amdgcn_mfma_f32_16x16x32_bf16(ah1, bh1, acc, 0, 0, 0);
    acc = __builtin_amdgcn_mfma_f32_16x16x32_bf16(ah2, bh2, acc, 0, 0, 0);
    acc = __builtin_amdgcn_mfma_f32_16x16x32_bf16(ah3, bh3, acc, 0, 0, 0);
    float4 hs = *(const float4*)&hsq[base + t * 16 + kg * 4];
    float hsa[4] = {hs.x, hs.y, hs.z, hs.w};
#pragma unroll
    for (int r = 0; r < 4; ++r) {
      float tv = acc[r] - hsa[r] + 512.0f;
      bool pass = tv >= myThr;
      unsigned long long mask = __ballot(pass);
      if (mask) {
        int pos = wbase + (int)__popcll(mask & ltmask);
        if (pass && pos < WBUF)
          buf[w][pos] = ((unsigned)qcol << 12) | (unsigned)(t * 16 + kg * 4 + r);
        wbase += (int)__popcll(mask);
      }
    }
  }
  if (wbase > WBUF) wbase = WBUF;
  __syncthreads();

  for (int i = lane; i < wbase; i += 64) {
    unsigned int e = buf[w][i];
    int ql = (int)(e >> 12);
    unsigned int slot = atomicAdd(&qc[w][ql], 1u);
    if (slot < CAPH)
      cand[(size_t)(base + qg * 64 + w * 16 + ql) * (2 * CAPH) + ht * CAPH + slot] =
          (unsigned short)(e & 0xfffu);
  }
  __syncthreads();

  if (lane < 16) {
    unsigned int c = qc[w][lane];
    if (c > CAPH) c = CAPH;
    qcnt[(size_t)(base + qg * 64 + w * 16 + lane) * 2 + ht] = (unsigned short)c;
  }
}

// ---------------------------------------------------------------------------
// Exact f32 rerank of <=256 survivors -> top-16 (val desc, idx asc tie-break)
__launch_bounds__(256)
__global__ void k_rerank(const float* __restrict__ xt, const float* __restrict__ hsq,
                         const unsigned short* __restrict__ cand,
                         const unsigned short* __restrict__ qcnt,
                         unsigned short* __restrict__ nbr) {
  int wq = blockIdx.x * 4 + (threadIdx.x >> 6);
  int lane = threadIdx.x & 63;
  int b = wq >> 12;
  int base = b * NN;
  int n0 = qcnt[(size_t)wq * 2];
  int n1 = qcnt[(size_t)wq * 2 + 1];
  int nt = n0 + n1;
  const float* qr = xt + (size_t)wq * CC;

  float vs[4]; int is[4];
#pragma unroll
  for (int s = 0; s < 4; ++s) { vs[s] = -3.4e38f; is[s] = 0x7fffffff; }

#pragma unroll
  for (int s = 0; s < 4; ++s) {
    int j = lane + s * 64;
    if (j < nt) {
      int c = (j < n0) ? cand[(size_t)wq * (2 * CAPH) + j]
                       : cand[(size_t)wq * (2 * CAPH) + CAPH + (j - n0)];
      const float* cr = xt + (size_t)(base + c) * CC;
      float acc = 0.f;
#pragma unroll
      for (int cc = 0; cc < CC; cc += 4) {
        float4 qa = *(const float4*)&qr[cc];
        float4 ca = *(const float4*)&cr[cc];
        acc = fmaf(qa.x, ca.x, acc);
        acc = fmaf(qa.y, ca.y, acc);
        acc = fmaf(qa.z, ca.z, acc);
        acc = fmaf(qa.w, ca.w, acc);
      }
      vs[s] = acc - hsq[base + c];
      is[s] = c;
    }
  }

  unsigned short* o = nbr + (size_t)wq * KK;
  for (int s = 0; s < KK; ++s) {
    float bv = vs[0]; int bi_ = is[0];
#pragma unroll
    for (int t = 1; t < 4; ++t)
      if ((vs[t] > bv) || (vs[t] == bv && is[t] < bi_)) { bv = vs[t]; bi_ = is[t]; }
#pragma unroll
    for (int off = 1; off < 64; off <<= 1) {
      float ov = __shfl_xor(bv, off, 64);
      int oi = __shfl_xor(bi_, off, 64);
      bool take = (ov > bv) || (ov == bv && oi < bi_);
      bv = take ? ov : bv;
      bi_ = take ? oi : bi_;
    }
    if (lane == 0) o[s] = (unsigned short)bi_;
#pragma unroll
    for (int t = 0; t < 4; ++t)
      if (is[t] == bi_) { vs[t] = -3.4e38f; is[t] = 0x7fffffff; }
  }
}

// ---------------------------------------------------------------------------
// h = xt . W via 3-term split-bf16 MFMA (xhi*Whi + xhi*Wlo + xlo*Whi), bf16 out
__launch_bounds__(256)
__global__ void k_h2(const float* __restrict__ xt,
                     const unsigned short* __restrict__ Whi,
                     const unsigned short* __restrict__ Wlo,
                     unsigned short* __restrict__ hout) {
  int w = threadIdx.x >> 6, lane = threadIdx.x & 63;
  int r16 = lane & 15, kg = lane >> 4;
  int nd0 = blockIdx.x * 64 + w * 16;
  const float* arow = xt + (size_t)(nd0 + r16) * CC;
  short8v ahi[4], alo[4];
#pragma unroll
  for (int ks = 0; ks < 4; ++ks) {
    float4 f0 = *(const float4*)&arow[ks * 32 + kg * 8];
    float4 f1 = *(const float4*)&arow[ks * 32 + kg * 8 + 4];
    float fv[8] = {f0.x, f0.y, f0.z, f0.w, f1.x, f1.y, f1.z, f1.w};
    short8v hh_, ll_;
#pragma unroll
    for (int j = 0; j < 8; ++j) {
      unsigned short hb = f2bf(fv[j]);
      hh_[j] = (short)hb;
      ll_[j] = (short)f2bf(fv[j] - bf2f(hb));
    }
    ahi[ks] = hh_; alo[ks] = ll_;
  }
  const short8v* WH = (const short8v*)Whi;   // granule: hf*16 + ks*4 + kg
  const short8v* WL = (const short8v*)Wlo;
#pragma unroll 1
  for (int ct = 0; ct < 32; ++ct) {
    int hf = ct * 16 + r16;
    f32x4 acc = {0.f, 0.f, 0.f, 0.f};
#pragma unroll
    for (int ks = 0; ks < 4; ++ks) {
      short8v bh = WH[(size_t)hf * 16 + ks * 4 + kg];
      short8v bl = WL[(size_t)hf * 16 + ks * 4 + kg];
      acc = __builtin_amdgcn_mfma_f32_16x16x32_bf16(ahi[ks], bh, acc, 0, 0, 0);
      acc = __builtin_amdgcn_mfma_f32_16x16x32_bf16(ahi[ks], bl, acc, 0, 0, 0);
      acc = __builtin_amdgcn_mfma_f32_16x16x32_bf16(alo[ks], bh, acc, 0, 0, 0);
    }
#pragma unroll
    for (int r = 0; r < 4; ++r)
      hout[(size_t)(nd0 + kg * 4 + r) * HF + hf] = f2bf(acc[r]);
  }
}

// ---------------------------------------------------------------------------
// a_src/a_dst[b][n][h] = sum_f h[b][n][h][f] * att_{src,dst}[h][f]
__global__ void k_att(const unsigned short* __restrict__ h,
                      const float* __restrict__ att_src, const float* __restrict__ att_dst,
                      float* __restrict__ a_src, float* __restrict__ a_dst) {
  int gid = blockIdx.x * 256 + threadIdx.x;
  int wid = gid >> 6;            // node index b*N+n
  int lane = threadIdx.x & 63;
  uint4 v = ((const uint4*)(h + (size_t)wid * HF))[lane];
  float hv[8];
  hv[0] = bf2f(v.x & 0xffff); hv[1] = bf2f(v.x >> 16);
  hv[2] = bf2f(v.y & 0xffff); hv[3] = bf2f(v.y >> 16);
  hv[4] = bf2f(v.z & 0xffff); hv[5] = bf2f(v.z >> 16);
  hv[6] = bf2f(v.w & 0xffff); hv[7] = bf2f(v.w >> 16);
  int base = lane * 8;
  float s = 0.f, d = 0.f;
#pragma unroll
  for (int i = 0; i < 8; ++i) {
    s += hv[i] * att_src[base + i];
    d += hv[i] * att_dst[base + i];
  }
#pragma unroll
  for (int off = 1; off < 16; off <<= 1) {
    s += __shfl_xor(s, off, 64);
    d += __shfl_xor(d, off, 64);
  }
  if ((lane & 15) == 0) {
    int hh = lane >> 4;
    a_src[wid * HH + hh] = s;
    a_dst[wid * HH + hh] = d;
  }
}

// ---------------------------------------------------------------------------
// gather + softmax(k=16) + weighted sum + head-mean + bias + transpose store
__launch_bounds__(256)
__global__ void k_out(const unsigned short* __restrict__ h,
                      const unsigned short* __restrict__ nbr,
                      const float* __restrict__ a_src, const float* __restrict__ a_dst,
                      const float* __restrict__ bias, float* __restrict__ out) {
  __shared__ float Ot[FF][17];
  int b = blockIdx.x >> 8, nb = blockIdx.x & 255;
  int w = threadIdx.x >> 6, lane = threadIdx.x & 63;
  int hh = lane >> 4, jj = lane & 15;

  for (int t = 0; t < 4; ++t) {
    int nl = w * 4 + t;
    int node = b * NN + nb * 16 + nl;
    int mj = nbr[node * KK + jj];

    float e = a_src[((size_t)b * NN + mj) * HH + hh] + a_dst[(size_t)node * HH + hh];
    e = e >= 0.f ? e : 0.2f * e;
    float m = e;
#pragma unroll
    for (int off = 1; off < 16; off <<= 1) m = fmaxf(m, __shfl_xor(m, off, 64));
    float p = expf(e - m);
    float sum = p;
#pragma unroll
    for (int off = 1; off < 16; off <<= 1) sum += __shfl_xor(sum, off, 64);
    float alpha = p / sum;

    float acc[8];
#pragma unroll
    for (int i = 0; i < 8; ++i) acc[i] = 0.f;

#pragma unroll
    for (int j = 0; j < 16; ++j) {
      float aj = __shfl(alpha, (hh << 4) | j, 64);
      int m2 = __shfl(mj, j, 64);
      uint4 v = ((const uint4*)(h + (size_t)(b * NN + m2) * HF))[lane];
      acc[0] += aj * bf2f(v.x & 0xffff); acc[1] += aj * bf2f(v.x >> 16);
      acc[2] += aj * bf2f(v.y & 0xffff); acc[3] += aj * bf2f(v.y >> 16);
      acc[4] += aj * bf2f(v.z & 0xffff); acc[5] += aj * bf2f(v.z >> 16);
      acc[6] += aj * bf2f(v.w & 0xffff); acc[7] += aj * bf2f(v.w >> 16);
    }

#pragma unroll
    for (int i = 0; i < 8; ++i) {
      acc[i] += __shfl_xor(acc[i], 16, 64);
      acc[i] += __shfl_xor(acc[i], 32, 64);
    }
    if (hh == 0) {
#pragma unroll
      for (int i = 0; i < 8; ++i) Ot[jj * 8 + i][nl] = acc[i] * 0.25f;
    }
  }
  __syncthreads();

#pragma unroll
  for (int it = 0; it < 8; ++it) {
    int idx = it * 256 + threadIdx.x;
    int f = idx >> 4, nl = idx & 15;
    out[((size_t)b * FF + f) * NN + nb * 16 + nl] = Ot[f][nl] + bias[f];
  }
}

// ---------------------------------------------------------------------------
extern "C" void kernel_launch(void* const* d_in, const int* in_sizes, int n_in,
                              void* d_out, int out_size, void* d_ws, size_t ws_size,
                              hipStream_t stream) {
  const float* x       = (const float*)d_in[0];
  const float* W       = (const float*)d_in[1];
  const float* att_src = (const float*)d_in[2];
  const float* att_dst = (const float*)d_in[3];
  const float* bias    = (const float*)d_in[4];

  char* ws = (char*)d_ws;
  // Lifetime-aliased layout; all sizes verified numerically:
  //   [0        ,16777216): xt    f32 32768*128*4 = 16,777,216 — split..rerank,h2
  //   [16777216 ,25165824): xhi   bf16 32768*128*2 = 8,388,608 — split..collect2
  //   [25165824 ,41943040): cand  u16 32768*256*2 = 16,777,216 — collect2..rerank
  //   [16777216 ,50331648): h     bf16 32768*512*2 = 33,554,432 — k_h2 AFTER rerank
  //   [50331648 ,51380224): nbr   u16 32768*16*2 = 1,048,576   — rerank..out
  //   [51380224 ,51511296): qcnt  u16 32768*2*2 = 131,072      — collect2..rerank
  //   [51511296 ,51642368): thr   f32 32768*4 = 131,072        — tauscan..collect2
  //   [51642368 ,51773440): hsq   f32 32768*4 = 131,072        — split..rerank
  //   [51773440 ,52297728): a_src f32 524,288 (aliased early by Whi+Wlo 2*131,072)
  //   [52297728 ,52822016): a_dst f32 524,288
  // total 52,822,016 B (same envelope as R4/R6 which allocated fine)
  float* xt            = (float*)ws;
  unsigned short* xhi  = (unsigned short*)(ws + 16777216);
  unsigned short* cand = (unsigned short*)(ws + 25165824);
  unsigned short* h    = (unsigned short*)(ws + 16777216);
  unsigned short* nbr  = (unsigned short*)(ws + 50331648);
  unsigned short* qcnt = (unsigned short*)(ws + 51380224);
  float* thr   = (float*)(ws + 51511296);
  float* hsq   = (float*)(ws + 51642368);
  float* a_src = (float*)(ws + 51773440);
  unsigned short* Whi  = (unsigned short*)(ws + 51773440);
  unsigned short* Wlo  = (unsigned short*)(ws + 51773440 + 131072);
  float* a_dst = (float*)(ws + 52297728);

  float* out = (float*)d_out;

  k_split   <<<BB * (NN / 64), 256, 0, stream>>>(x, xt, xhi, hsq);
  k_wpack   <<<HF * CC / 256, 256, 0, stream>>>(W, Whi, Wlo);
  k_tauscan <<<BB * 64, 256, 0, stream>>>(xhi, hsq, thr);
  k_collect2<<<BB * 64 * 2, 256, 0, stream>>>(xhi, hsq, thr, cand, qcnt);
  k_rerank  <<<BB * NN / 4, 256, 0, stream>>>(xt, hsq, cand, qcnt, nbr);
  k_h2      <<<BB * NN / 64, 256, 0, stream>>>(xt, Whi, Wlo, h);
  k_att     <<<BB * NN / 4, 256, 0, stream>>>(h, att_src, att_dst, a_src, a_dst);
  k_out     <<<BB * (NN / 16), 256, 0, stream>>>(h, nbr, a_src, a_dst, bias, out);
}

// Round 9
// 673.205 us; speedup vs baseline: 1.2198x; 1.0999x over previous
//
#include <hip/hip_runtime.h>
#include <hip/hip_bf16.h>

#define BB 8
#define CC 128
#define NN 4096
#define HH 4
#define FF 128
#define KK 16
#define HF 512      // H*F
#define CAPH 128    // survivor capacity per query per half (stride 256 total)
#define WBUF 1536   // per-wave compaction buffer entries (20 sigma)

typedef __attribute__((ext_vector_type(8))) short short8v;
typedef __attribute__((ext_vector_type(8))) unsigned short ushort8v;
typedef __attribute__((ext_vector_type(4))) float f32x4;

__device__ __forceinline__ float bf2f(unsigned int u) {
  return __uint_as_float(u << 16);
}

__device__ __forceinline__ unsigned short f2bf(float f) {
  unsigned int u = __float_as_uint(f);
  unsigned int lsb = (u >> 16) & 1u;
  u += 0x7fffu + lsb;                 // RTNE
  return (unsigned short)(u >> 16);
}

__device__ __forceinline__ unsigned int umin2(unsigned int a, unsigned int b) {
  return a < b ? a : b;
}
__device__ __forceinline__ unsigned int umin3(unsigned int a, unsigned int b, unsigned int c) {
  return umin2(umin2(a, b), c);
}

// async global->LDS, 16B per lane; lds base must be wave-uniform
__device__ __forceinline__ void gload16(const void* gsrc, void* ldst) {
  __builtin_amdgcn_global_load_lds(
      (const __attribute__((address_space(1))) unsigned int*)gsrc,
      (__attribute__((address_space(3))) unsigned int*)ldst, 16, 0, 0);
}

// ---------------------------------------------------------------------------
// x[b][c][n] -> xt[b][n][c] (f32), xhi[b][n][c] (bf16), hsq[b][n] = 0.5*|x|^2
__launch_bounds__(256)
__global__ void k_split(const float* __restrict__ x,
                        float* __restrict__ xt,
                        unsigned short* __restrict__ xhi,
                        float* __restrict__ hsq) {
  __shared__ float Ls[CC][65];
  int b = blockIdx.x >> 6, nb = blockIdx.x & 63;
  int n0 = nb * 64;
  int tid = threadIdx.x;
  const float* xb = x + (size_t)b * CC * NN;

  for (int i = tid; i < CC * 64; i += 256) {
    int c = i >> 6, nl = i & 63;
    Ls[c][nl] = xb[(size_t)c * NN + n0 + nl];
  }
  __syncthreads();

  int n = tid >> 2, part = tid & 3;     // 64 n x 4 parts (32 c each)
  int node = b * NN + n0 + n;
  float sum = 0.f;
#pragma unroll
  for (int g = 0; g < 4; ++g) {
    float v[8];
    ushort8v ph;
#pragma unroll
    for (int j = 0; j < 8; ++j) {
      int c = part * 32 + g * 8 + j;
      v[j] = Ls[c][n];
      ph[j] = f2bf(v[j]);
      sum += v[j] * v[j];
    }
    float4 f0 = {v[0], v[1], v[2], v[3]};
    float4 f1 = {v[4], v[5], v[6], v[7]};
    *(float4*)&xt[(size_t)node * CC + part * 32 + g * 8] = f0;
    *(float4*)&xt[(size_t)node * CC + part * 32 + g * 8 + 4] = f1;
    *(ushort8v*)&xhi[(size_t)node * CC + part * 32 + g * 8] = ph;
  }
  sum += __shfl_xor(sum, 1, 64);
  sum += __shfl_xor(sum, 2, 64);
  if (part == 0) hsq[node] = 0.5f * sum;
}

// ---------------------------------------------------------------------------
// Pack W[c][hf] f32 -> Whi/Wlo[hf][c] bf16
__global__ void k_wpack(const float* __restrict__ W,
                        unsigned short* __restrict__ Whi,
                        unsigned short* __restrict__ Wlo) {
  int i = blockIdx.x * 256 + threadIdx.x;   // over 512*128
  int hf = i >> 7, c = i & 127;
  float v = W[(size_t)c * HF + hf];
  unsigned short hb = f2bf(v);
  Whi[i] = hb;
  Wlo[i] = f2bf(v - bf2f(hb));
}

// ---------------------------------------------------------------------------
// tau scan over candidates 0..1023 (subset): LDS-staged tiles (double-buffered
// global_load_lds, XOR-preswizzled source, XOR-swizzled read). Per-lane insert
// top-16, merge 4 lanes -> 16th-best key; thr[q] = floor16(key) - 0.5.
__launch_bounds__(256)
__global__ void k_tauscan(const unsigned short* __restrict__ xhi,
                          const float* __restrict__ hsq,
                          float* __restrict__ thr) {
  __shared__ short8v AS[2][256];           // 8 KB staging (16 nodes x 16 granules)
  __shared__ unsigned int mv[4][16][64];   // 16 KB
  int b = blockIdx.x >> 6, qg = blockIdx.x & 63;
  int w = threadIdx.x >> 6, lane = threadIdx.x & 63;
  int qcol = lane & 15, kg = lane >> 4;
  int base = b * NN;
  int q = base + qg * 64 + w * 16 + qcol;

  const short8v* XH = (const short8v*)xhi;   // granules: node*16 + ks*4 + kg
  short8v bh0 = XH[(size_t)q * 16 + kg];
  short8v bh1 = XH[(size_t)q * 16 + 4 + kg];
  short8v bh2 = XH[(size_t)q * 16 + 8 + kg];
  short8v bh3 = XH[(size_t)q * 16 + 12 + kg];

  // staging geometry: this wave fills nodes 4w..4w+3; LDS linear slot
  // (node, j) holds global granule (j ^ node) of node  [involution]
  int snode = w * 4 + (lane >> 4);
  int sgran = (lane & 15) ^ (snode & 15);

  gload16(xhi + ((size_t)(base + snode)) * 128 + sgran * 8, &AS[0][w * 64]);
  __syncthreads();

  unsigned int bd[16];
  unsigned int worst = 0;
  int cur = 0;

#pragma unroll 1
  for (int lt = 0; lt < 64; ++lt) {
    if (lt + 1 < 64)
      gload16(xhi + ((size_t)(base + (lt + 1) * 16 + snode)) * 128 + sgran * 8,
              &AS[cur ^ 1][w * 64]);
    short8v ah0 = AS[cur][qcol * 16 + ((0 + kg) ^ qcol)];
    short8v ah1 = AS[cur][qcol * 16 + ((4 + kg) ^ qcol)];
    short8v ah2 = AS[cur][qcol * 16 + ((8 + kg) ^ qcol)];
    short8v ah3 = AS[cur][qcol * 16 + ((12 + kg) ^ qcol)];
    f32x4 acc = {0.f, 0.f, 0.f, 0.f};
    acc = __builtin_amdgcn_mfma_f32_16x16x32_bf16(ah0, bh0, acc, 0, 0, 0);
    acc = __builtin_amdgcn_mfma_f32_16x16x32_bf16(ah1, bh1, acc, 0, 0, 0);
    acc = __builtin_amdgcn_mfma_f32_16x16x32_bf16(ah2, bh2, acc, 0, 0, 0);
    acc = __builtin_amdgcn_mfma_f32_16x16x32_bf16(ah3, bh3, acc, 0, 0, 0);
    float4 hs = *(const float4*)&hsq[base + lt * 16 + kg * 4];
    float hsa[4] = {hs.x, hs.y, hs.z, hs.w};

    if (lt < 4) {
#pragma unroll
      for (int r = 0; r < 4; ++r) {
        float tv = acc[r] - hsa[r] + 512.0f;
        bd[lt * 4 + r] = (__float_as_uint(tv) & ~1023u) | (1023u - (unsigned)(lt * 4 + r));
      }
      if (lt == 3) {
        unsigned int m0 = umin3(bd[0], bd[1], bd[2]);
        m0 = umin3(m0, bd[3], bd[4]);
        m0 = umin3(m0, bd[5], bd[6]);
        m0 = umin2(m0, bd[7]);
        unsigned int m1 = umin3(bd[8], bd[9], bd[10]);
        m1 = umin3(m1, bd[11], bd[12]);
        m1 = umin3(m1, bd[13], bd[14]);
        m1 = umin2(m1, bd[15]);
        worst = umin2(m0, m1);
      }
    } else {
#pragma unroll
      for (int r = 0; r < 4; ++r) {
        float tv = acc[r] - hsa[r] + 512.0f;
        unsigned int key = (__float_as_uint(tv) & ~1023u) | (1023u - (unsigned)(lt * 4 + r));
        if (key > worst) {
#pragma unroll
          for (int i = 0; i < 16; ++i) bd[i] = (bd[i] == worst) ? key : bd[i];
          unsigned int n0_ = umin3(bd[0], bd[1], bd[2]);
          n0_ = umin3(n0_, bd[3], bd[4]);
          n0_ = umin3(n0_, bd[5], bd[6]);
          n0_ = umin2(n0_, bd[7]);
          unsigned int n1_ = umin3(bd[8], bd[9], bd[10]);
          n1_ = umin3(n1_, bd[11], bd[12]);
          n1_ = umin3(n1_, bd[13], bd[14]);
          n1_ = umin2(n1_, bd[15]);
          worst = umin2(n0_, n1_);
        }
      }
    }
    __syncthreads();
    cur ^= 1;
  }

#pragma unroll
  for (int i = 0; i < 16; ++i) mv[w][qcol][kg * 16 + i] = bd[i];
  __syncthreads();

  if (lane < 16) {
    unsigned int tb[16];
#pragma unroll
    for (int i = 0; i < 16; ++i) tb[i] = mv[w][lane][i];
    unsigned int w0 = umin3(tb[0], tb[1], tb[2]);
    w0 = umin3(w0, tb[3], tb[4]);
    w0 = umin3(w0, tb[5], tb[6]);
    w0 = umin2(w0, tb[7]);
    unsigned int w1 = umin3(tb[8], tb[9], tb[10]);
    w1 = umin3(w1, tb[11], tb[12]);
    w1 = umin3(w1, tb[13], tb[14]);
    w1 = umin2(w1, tb[15]);
    unsigned int wst = umin2(w0, w1);
    for (int j = 16; j < 64; ++j) {
      unsigned int v = mv[w][lane][j];
      if (v > wst) {
        bool done = false;
#pragma unroll
        for (int i = 0; i < 16; ++i) {
          bool m = (!done) && (tb[i] == wst);
          done = done || m;
          tb[i] = m ? v : tb[i];
        }
        unsigned int a0 = umin3(tb[0], tb[1], tb[2]);
        a0 = umin3(a0, tb[3], tb[4]);
        a0 = umin3(a0, tb[5], tb[6]);
        a0 = umin2(a0, tb[7]);
        unsigned int a1 = umin3(tb[8], tb[9], tb[10]);
        a1 = umin3(a1, tb[11], tb[12]);
        a1 = umin3(a1, tb[13], tb[14]);
        a1 = umin2(a1, tb[15]);
        wst = umin2(a0, a1);
      }
    }
    thr[base + qg * 64 + w * 16 + lane] = __uint_as_float(wst & ~1023u) - 0.5f;
  }
}

// ---------------------------------------------------------------------------
// Collect survivors (tv >= thr[q]): LDS-staged tiles + ballot-compaction into
// per-wave LDS list, then bucket into per-(query,half) global lists.
__launch_bounds__(256)
__global__ void k_collect2(const unsigned short* __restrict__ xhi,
                           const float* __restrict__ hsq,
                           const float* __restrict__ thr,
                           unsigned short* __restrict__ cand,
                           unsigned short* __restrict__ qcnt) {
  __shared__ short8v AS[2][256];          // 8 KB staging
  __shared__ unsigned int buf[4][WBUF];   // 24 KB
  __shared__ unsigned int qc[4][16];
  int bx = blockIdx.x;
  int b = bx >> 7, rest = bx & 127;
  int qg = rest >> 1, ht = rest & 1;
  int w = threadIdx.x >> 6, lane = threadIdx.x & 63;
  int qcol = lane & 15, kg = lane >> 4;
  int base = b * NN;
  int q = base + qg * 64 + w * 16 + qcol;

  const short8v* XH = (const short8v*)xhi;
  short8v bh0 = XH[(size_t)q * 16 + kg];
  short8v bh1 = XH[(size_t)q * 16 + 4 + kg];
  short8v bh2 = XH[(size_t)q * 16 + 8 + kg];
  short8v bh3 = XH[(size_t)q * 16 + 12 + kg];
  float myThr = thr[q];
  if (lane < 16) qc[w][lane] = 0;

  int snode = w * 4 + (lane >> 4);
  int sgran = (lane & 15) ^ (snode & 15);

  gload16(xhi + ((size_t)(base + (ht * 128) * 16 + snode)) * 128 + sgran * 8,
          &AS[0][w * 64]);
  __syncthreads();

  int wbase = 0;
  unsigned long long ltmask = (1ull << lane) - 1ull;
  int cur = 0;

#pragma unroll 1
  for (int lt = 0; lt < 128; ++lt) {
    int t = ht * 128 + lt;
    if (lt + 1 < 128)
      gload16(xhi + ((size_t)(base + (t + 1) * 16 + snode)) * 128 + sgran * 8,
              &AS[cur ^ 1][w * 64]);
    short8v ah0 = AS[cur][qcol * 16 + ((0 + kg) ^ qcol)];
    short8v ah1 = AS[cur][qcol * 16 + ((4 + kg) ^ qcol)];
    short8v ah2 = AS[cur][qcol * 16 + ((8 + kg) ^ qcol)];
    short8v ah3 = AS[cur][qcol * 16 + ((12 + kg) ^ qcol)];
    f32x4 acc = {0.f, 0.f, 0.f, 0.f};
    acc = __builtin_amdgcn_mfma_f32_16x16x32_bf16(ah0, bh0, acc, 0, 0, 0);
    acc = __builtin_amdgcn_mfma_f32_16x16x32_bf16(ah1, bh1, acc, 0, 0, 0);
    acc = __builtin_amdgcn_mfma_f32_16x16x32_bf16(ah2, bh2, acc, 0, 0, 0);
    acc = __builtin_amdgcn_mfma_f32_16x16x32_bf16(ah3, bh3, acc, 0, 0, 0);
    float4 hs = *(const float4*)&hsq[base + t * 16 + kg * 4];
    float hsa[4] = {hs.x, hs.y, hs.z, hs.w};
#pragma unroll
    for (int r = 0; r < 4; ++r) {
      float tv = acc[r] - hsa[r] + 512.0f;
      bool pass = tv >= myThr;
      unsigned long long mask = __ballot(pass);
      if (mask) {
        int pos = wbase + (int)__popcll(mask & ltmask);
        if (pass && pos < WBUF)
          buf[w][pos] = ((unsigned)qcol << 12) | (unsigned)(t * 16 + kg * 4 + r);
        wbase += (int)__popcll(mask);
      }
    }
    __syncthreads();
    cur ^= 1;
  }
  if (wbase > WBUF) wbase = WBUF;

  for (int i = lane; i < wbase; i += 64) {
    unsigned int e = buf[w][i];
    int ql = (int)(e >> 12);
    unsigned int slot = atomicAdd(&qc[w][ql], 1u);
    if (slot < CAPH)
      cand[(size_t)(base + qg * 64 + w * 16 + ql) * (2 * CAPH) + ht * CAPH + slot] =
          (unsigned short)(e & 0xfffu);
  }
  __syncthreads();

  if (lane < 16) {
    unsigned int c = qc[w][lane];
    if (c > CAPH) c = CAPH;
    qcnt[(size_t)(base + qg * 64 + w * 16 + lane) * 2 + ht] = (unsigned short)c;
  }
}

// ---------------------------------------------------------------------------
// Cooperative exact f32 rerank: wave per query, serial over survivors; per
// candidate the wave loads the 512B row coalesced (8B/lane), 2 fma + 6-shfl
// butterfly reduce. Then 16x (val desc, idx asc) selection as before.
__launch_bounds__(256)
__global__ void k_rerank(const float* __restrict__ xt, const float* __restrict__ hsq,
                         const unsigned short* __restrict__ cand,
                         const unsigned short* __restrict__ qcnt,
                         unsigned short* __restrict__ nbr) {
  int wq = blockIdx.x * 4 + (threadIdx.x >> 6);
  int lane = threadIdx.x & 63;
  int b = wq >> 12;
  int base = b * NN;
  int n0 = qcnt[(size_t)wq * 2];
  int n1 = qcnt[(size_t)wq * 2 + 1];
  int nt = n0 + n1;
  const float* qr = xt + (size_t)wq * CC;
  float2 qv = *(const float2*)&qr[lane * 2];

  float vs[4]; int is[4];
#pragma unroll
  for (int s = 0; s < 4; ++s) { vs[s] = -3.4e38f; is[s] = 0x7fffffff; }

#pragma unroll
  for (int s = 0; s < 4; ++s) {
#pragma unroll 1
    for (int jj = 0; jj < 64; ++jj) {
      int j = s * 64 + jj;
      if (j >= nt) break;                          // wave-uniform
      int c = (j < n0) ? cand[(size_t)wq * (2 * CAPH) + j]
                       : cand[(size_t)wq * (2 * CAPH) + CAPH + (j - n0)];
      float2 cv = *(const float2*)&xt[(size_t)(base + c) * CC + lane * 2];
      float d = fmaf(qv.x, cv.x, qv.y * cv.y);
#pragma unroll
      for (int off = 1; off < 64; off <<= 1) d += __shfl_xor(d, off, 64);
      float val = d - hsq[base + c];
      if (lane == jj) { vs[s] = val; is[s] = c; }
    }
  }

  unsigned short* o = nbr + (size_t)wq * KK;
  for (int s = 0; s < KK; ++s) {
    float bv = vs[0]; int bi_ = is[0];
#pragma unroll
    for (int t = 1; t < 4; ++t)
      if ((vs[t] > bv) || (vs[t] == bv && is[t] < bi_)) { bv = vs[t]; bi_ = is[t]; }
#pragma unroll
    for (int off = 1; off < 64; off <<= 1) {
      float ov = __shfl_xor(bv, off, 64);
      int oi = __shfl_xor(bi_, off, 64);
      bool take = (ov > bv) || (ov == bv && oi < bi_);
      bv = take ? ov : bv;
      bi_ = take ? oi : bi_;
    }
    if (lane == 0) o[s] = (unsigned short)bi_;
#pragma unroll
    for (int t = 0; t < 4; ++t)
      if (is[t] == bi_) { vs[t] = -3.4e38f; is[t] = 0x7fffffff; }
  }
}

// ---------------------------------------------------------------------------
// h = xt . W via 3-term split-bf16 MFMA (xhi*Whi + xhi*Wlo + xlo*Whi), bf16 out
__launch_bounds__(256)
__global__ void k_h2(const float* __restrict__ xt,
                     const unsigned short* __restrict__ Whi,
                     const unsigned short* __restrict__ Wlo,
                     unsigned short* __restrict__ hout) {
  int w = threadIdx.x >> 6, lane = threadIdx.x & 63;
  int r16 = lane & 15, kg = lane >> 4;
  int nd0 = blockIdx.x * 64 + w * 16;
  const float* arow = xt + (size_t)(nd0 + r16) * CC;
  short8v ahi[4], alo[4];
#pragma unroll
  for (int ks = 0; ks < 4; ++ks) {
    float4 f0 = *(const float4*)&arow[ks * 32 + kg * 8];
    float4 f1 = *(const float4*)&arow[ks * 32 + kg * 8 + 4];
    float fv[8] = {f0.x, f0.y, f0.z, f0.w, f1.x, f1.y, f1.z, f1.w};
    short8v hh_, ll_;
#pragma unroll
    for (int j = 0; j < 8; ++j) {
      unsigned short hb = f2bf(fv[j]);
      hh_[j] = (short)hb;
      ll_[j] = (short)f2bf(fv[j] - bf2f(hb));
    }
    ahi[ks] = hh_; alo[ks] = ll_;
  }
  const short8v* WH = (const short8v*)Whi;   // granule: hf*16 + ks*4 + kg
  const short8v* WL = (const short8v*)Wlo;
#pragma unroll 1
  for (int ct = 0; ct < 32; ++ct) {
    int hf = ct * 16 + r16;
    f32x4 acc = {0.f, 0.f, 0.f, 0.f};
#pragma unroll
    for (int ks = 0; ks < 4; ++ks) {
      short8v bh = WH[(size_t)hf * 16 + ks * 4 + kg];
      short8v bl = WL[(size_t)hf * 16 + ks * 4 + kg];
      acc = __builtin_amdgcn_mfma_f32_16x16x32_bf16(ahi[ks], bh, acc, 0, 0, 0);
      acc = __builtin_amdgcn_mfma_f32_16x16x32_bf16(ahi[ks], bl, acc, 0, 0, 0);
      acc = __builtin_amdgcn_mfma_f32_16x16x32_bf16(alo[ks], bh, acc, 0, 0, 0);
    }
#pragma unroll
    for (int r = 0; r < 4; ++r)
      hout[(size_t)(nd0 + kg * 4 + r) * HF + hf] = f2bf(acc[r]);
  }
}

// ---------------------------------------------------------------------------
// a_src/a_dst[b][n][h] = sum_f h[b][n][h][f] * att_{src,dst}[h][f]
__global__ void k_att(const unsigned short* __restrict__ h,
                      const float* __restrict__ att_src, const float* __restrict__ att_dst,
                      float* __restrict__ a_src, float* __restrict__ a_dst) {
  int gid = blockIdx.x * 256 + threadIdx.x;
  int wid = gid >> 6;            // node index b*N+n
  int lane = threadIdx.x & 63;
  uint4 v = ((const uint4*)(h + (size_t)wid * HF))[lane];
  float hv[8];
  hv[0] = bf2f(v.x & 0xffff); hv[1] = bf2f(v.x >> 16);
  hv[2] = bf2f(v.y & 0xffff); hv[3] = bf2f(v.y >> 16);
  hv[4] = bf2f(v.z & 0xffff); hv[5] = bf2f(v.z >> 16);
  hv[6] = bf2f(v.w & 0xffff); hv[7] = bf2f(v.w >> 16);
  int base = lane * 8;
  float s = 0.f, d = 0.f;
#pragma unroll
  for (int i = 0; i < 8; ++i) {
    s += hv[i] * att_src[base + i];
    d += hv[i] * att_dst[base + i];
  }
#pragma unroll
  for (int off = 1; off < 16; off <<= 1) {
    s += __shfl_xor(s, off, 64);
    d += __shfl_xor(d, off, 64);
  }
  if ((lane & 15) == 0) {
    int hh = lane >> 4;
    a_src[wid * HH + hh] = s;
    a_dst[wid * HH + hh] = d;
  }
}

// ---------------------------------------------------------------------------
// gather + softmax(k=16) + weighted sum + head-mean + bias + transpose store
__launch_bounds__(256)
__global__ void k_out(const unsigned short* __restrict__ h,
                      const unsigned short* __restrict__ nbr,
                      const float* __restrict__ a_src, const float* __restrict__ a_dst,
                      const float* __restrict__ bias, float* __restrict__ out) {
  __shared__ float Ot[FF][17];
  int b = blockIdx.x >> 8, nb = blockIdx.x & 255;
  int w = threadIdx.x >> 6, lane = threadIdx.x & 63;
  int hh = lane >> 4, jj = lane & 15;

  for (int t = 0; t < 4; ++t) {
    int nl = w * 4 + t;
    int node = b * NN + nb * 16 + nl;
    int mj = nbr[node * KK + jj];

    float e = a_src[((size_t)b * NN + mj) * HH + hh] + a_dst[(size_t)node * HH + hh];
    e = e >= 0.f ? e : 0.2f * e;
    float m = e;
#pragma unroll
    for (int off = 1; off < 16; off <<= 1) m = fmaxf(m, __shfl_xor(m, off, 64));
    float p = expf(e - m);
    float sum = p;
#pragma unroll
    for (int off = 1; off < 16; off <<= 1) sum += __shfl_xor(sum, off, 64);
    float alpha = p / sum;

    float acc[8];
#pragma unroll
    for (int i = 0; i < 8; ++i) acc[i] = 0.f;

#pragma unroll
    for (int j = 0; j < 16; ++j) {
      float aj = __shfl(alpha, (hh << 4) | j, 64);
      int m2 = __shfl(mj, j, 64);
      uint4 v = ((const uint4*)(h + (size_t)(b * NN + m2) * HF))[lane];
      acc[0] += aj * bf2f(v.x & 0xffff); acc[1] += aj * bf2f(v.x >> 16);
      acc[2] += aj * bf2f(v.y & 0xffff); acc[3] += aj * bf2f(v.y >> 16);
      acc[4] += aj * bf2f(v.z & 0xffff); acc[5] += aj * bf2f(v.z >> 16);
      acc[6] += aj * bf2f(v.w & 0xffff); acc[7] += aj * bf2f(v.w >> 16);
    }

#pragma unroll
    for (int i = 0; i < 8; ++i) {
      acc[i] += __shfl_xor(acc[i], 16, 64);
      acc[i] += __shfl_xor(acc[i], 32, 64);
    }
    if (hh == 0) {
#pragma unroll
      for (int i = 0; i < 8; ++i) Ot[jj * 8 + i][nl] = acc[i] * 0.25f;
    }
  }
  __syncthreads();

#pragma unroll
  for (int it = 0; it < 8; ++it) {
    int idx = it * 256 + threadIdx.x;
    int f = idx >> 4, nl = idx & 15;
    out[((size_t)b * FF + f) * NN + nb * 16 + nl] = Ot[f][nl] + bias[f];
  }
}

// ---------------------------------------------------------------------------
extern "C" void kernel_launch(void* const* d_in, const int* in_sizes, int n_in,
                              void* d_out, int out_size, void* d_ws, size_t ws_size,
                              hipStream_t stream) {
  const float* x       = (const float*)d_in[0];
  const float* W       = (const float*)d_in[1];
  const float* att_src = (const float*)d_in[2];
  const float* att_dst = (const float*)d_in[3];
  const float* bias    = (const float*)d_in[4];

  char* ws = (char*)d_ws;
  // Lifetime-aliased layout; all sizes verified numerically (same as R8):
  //   [0        ,16777216): xt    f32 32768*128*4 = 16,777,216 — split..rerank,h2
  //   [16777216 ,25165824): xhi   bf16 32768*128*2 = 8,388,608 — split..collect2
  //   [25165824 ,41943040): cand  u16 32768*256*2 = 16,777,216 — collect2..rerank
  //   [16777216 ,50331648): h     bf16 32768*512*2 = 33,554,432 — k_h2 AFTER rerank
  //   [50331648 ,51380224): nbr   u16 32768*16*2 = 1,048,576   — rerank..out
  //   [51380224 ,51511296): qcnt  u16 32768*2*2 = 131,072      — collect2..rerank
  //   [51511296 ,51642368): thr   f32 32768*4 = 131,072        — tauscan..collect2
  //   [51642368 ,51773440): hsq   f32 32768*4 = 131,072        — split..rerank
  //   [51773440 ,52297728): a_src f32 524,288 (aliased early by Whi+Wlo 2*131,072)
  //   [52297728 ,52822016): a_dst f32 524,288
  // total 52,822,016 B (proven envelope)
  float* xt            = (float*)ws;
  unsigned short* xhi  = (unsigned short*)(ws + 16777216);
  unsigned short* cand = (unsigned short*)(ws + 25165824);
  unsigned short* h    = (unsigned short*)(ws + 16777216);
  unsigned short* nbr  = (unsigned short*)(ws + 50331648);
  unsigned short* qcnt = (unsigned short*)(ws + 51380224);
  float* thr   = (float*)(ws + 51511296);
  float* hsq   = (float*)(ws + 51642368);
  float* a_src = (float*)(ws + 51773440);
  unsigned short* Whi  = (unsigned short*)(ws + 51773440);
  unsigned short* Wlo  = (unsigned short*)(ws + 51773440 + 131072);
  float* a_dst = (float*)(ws + 52297728);

  float* out = (float*)d_out;

  k_split   <<<BB * (NN / 64), 256, 0, stream>>>(x, xt, xhi, hsq);
  k_wpack   <<<HF * CC / 256, 256, 0, stream>>>(W, Whi, Wlo);
  k_tauscan <<<BB * 64, 256, 0, stream>>>(xhi, hsq, thr);
  k_collect2<<<BB * 64 * 2, 256, 0, stream>>>(xhi, hsq, thr, cand, qcnt);
  k_rerank  <<<BB * NN / 4, 256, 0, stream>>>(xt, hsq, cand, qcnt, nbr);
  k_h2      <<<BB * NN / 64, 256, 0, stream>>>(xt, Whi, Wlo, h);
  k_att     <<<BB * NN / 4, 256, 0, stream>>>(h, att_src, att_dst, a_src, a_dst);
  k_out     <<<BB * (NN / 16), 256, 0, stream>>>(h, nbr, a_src, a_dst, bias, out);
}

// Round 10
// 470.040 us; speedup vs baseline: 1.7471x; 1.4322x over previous
//
#include <hip/hip_runtime.h>
#include <hip/hip_bf16.h>

#define BB 8
#define CC 128
#define NN 4096
#define HH 4
#define FF 128
#define KK 16
#define HF 512      // H*F
#define CAPH 128    // survivor capacity per query per half (stride 256 total)
#define WBUF 1536   // per-wave compaction buffer entries (20 sigma)

typedef __attribute__((ext_vector_type(8))) short short8v;
typedef __attribute__((ext_vector_type(8))) unsigned short ushort8v;
typedef __attribute__((ext_vector_type(4))) float f32x4;

__device__ __forceinline__ float bf2f(unsigned int u) {
  return __uint_as_float(u << 16);
}

__device__ __forceinline__ unsigned short f2bf(float f) {
  unsigned int u = __float_as_uint(f);
  unsigned int lsb = (u >> 16) & 1u;
  u += 0x7fffu + lsb;                 // RTNE
  return (unsigned short)(u >> 16);
}

__device__ __forceinline__ unsigned int umin2(unsigned int a, unsigned int b) {
  return a < b ? a : b;
}
__device__ __forceinline__ unsigned int umin3(unsigned int a, unsigned int b, unsigned int c) {
  return umin2(umin2(a, b), c);
}

// async global->LDS, 16B per lane; lds base must be wave-uniform
__device__ __forceinline__ void gload16(const void* gsrc, void* ldst) {
  __builtin_amdgcn_global_load_lds(
      (const __attribute__((address_space(1))) unsigned int*)gsrc,
      (__attribute__((address_space(3))) unsigned int*)ldst, 16, 0, 0);
}

// ---------------------------------------------------------------------------
// x[b][c][n] -> xt[b][n][c] (f32), xhi[b][n][c] (bf16), hsq[b][n] = 0.5*|x|^2
__launch_bounds__(256)
__global__ void k_split(const float* __restrict__ x,
                        float* __restrict__ xt,
                        unsigned short* __restrict__ xhi,
                        float* __restrict__ hsq) {
  __shared__ float Ls[CC][65];
  int b = blockIdx.x >> 6, nb = blockIdx.x & 63;
  int n0 = nb * 64;
  int tid = threadIdx.x;
  const float* xb = x + (size_t)b * CC * NN;

  for (int i = tid; i < CC * 64; i += 256) {
    int c = i >> 6, nl = i & 63;
    Ls[c][nl] = xb[(size_t)c * NN + n0 + nl];
  }
  __syncthreads();

  int n = tid >> 2, part = tid & 3;     // 64 n x 4 parts (32 c each)
  int node = b * NN + n0 + n;
  float sum = 0.f;
#pragma unroll
  for (int g = 0; g < 4; ++g) {
    float v[8];
    ushort8v ph;
#pragma unroll
    for (int j = 0; j < 8; ++j) {
      int c = part * 32 + g * 8 + j;
      v[j] = Ls[c][n];
      ph[j] = f2bf(v[j]);
      sum += v[j] * v[j];
    }
    float4 f0 = {v[0], v[1], v[2], v[3]};
    float4 f1 = {v[4], v[5], v[6], v[7]};
    *(float4*)&xt[(size_t)node * CC + part * 32 + g * 8] = f0;
    *(float4*)&xt[(size_t)node * CC + part * 32 + g * 8 + 4] = f1;
    *(ushort8v*)&xhi[(size_t)node * CC + part * 32 + g * 8] = ph;
  }
  sum += __shfl_xor(sum, 1, 64);
  sum += __shfl_xor(sum, 2, 64);
  if (part == 0) hsq[node] = 0.5f * sum;
}

// ---------------------------------------------------------------------------
// Pack W[c][hf] f32 -> Whi/Wlo[hf][c] bf16
__global__ void k_wpack(const float* __restrict__ W,
                        unsigned short* __restrict__ Whi,
                        unsigned short* __restrict__ Wlo) {
  int i = blockIdx.x * 256 + threadIdx.x;   // over 512*128
  int hf = i >> 7, c = i & 127;
  float v = W[(size_t)c * HF + hf];
  unsigned short hb = f2bf(v);
  Whi[i] = hb;
  Wlo[i] = f2bf(v - bf2f(hb));
}

// ---------------------------------------------------------------------------
// tau scan over candidates 0..1023 (subset): LDS-staged tiles (double-buffered
// global_load_lds, XOR-preswizzled source, XOR-swizzled read). Per-lane insert
// top-16, merge 4 lanes -> 16th-best key; thr[q] = floor16(key) - 0.5.
__launch_bounds__(256)
__global__ void k_tauscan(const unsigned short* __restrict__ xhi,
                          const float* __restrict__ hsq,
                          float* __restrict__ thr) {
  __shared__ short8v AS[2][256];           // 8 KB staging (16 nodes x 16 granules)
  __shared__ unsigned int mv[4][16][64];   // 16 KB
  int b = blockIdx.x >> 6, qg = blockIdx.x & 63;
  int w = threadIdx.x >> 6, lane = threadIdx.x & 63;
  int qcol = lane & 15, kg = lane >> 4;
  int base = b * NN;
  int q = base + qg * 64 + w * 16 + qcol;

  const short8v* XH = (const short8v*)xhi;   // granules: node*16 + ks*4 + kg
  short8v bh0 = XH[(size_t)q * 16 + kg];
  short8v bh1 = XH[(size_t)q * 16 + 4 + kg];
  short8v bh2 = XH[(size_t)q * 16 + 8 + kg];
  short8v bh3 = XH[(size_t)q * 16 + 12 + kg];

  // staging geometry: this wave fills nodes 4w..4w+3; LDS linear slot
  // (node, j) holds global granule (j ^ node) of node  [involution]
  int snode = w * 4 + (lane >> 4);
  int sgran = (lane & 15) ^ (snode & 15);

  gload16(xhi + ((size_t)(base + snode)) * 128 + sgran * 8, &AS[0][w * 64]);
  __syncthreads();

  unsigned int bd[16];
  unsigned int worst = 0;
  int cur = 0;

#pragma unroll 1
  for (int lt = 0; lt < 64; ++lt) {
    if (lt + 1 < 64)
      gload16(xhi + ((size_t)(base + (lt + 1) * 16 + snode)) * 128 + sgran * 8,
              &AS[cur ^ 1][w * 64]);
    short8v ah0 = AS[cur][qcol * 16 + ((0 + kg) ^ qcol)];
    short8v ah1 = AS[cur][qcol * 16 + ((4 + kg) ^ qcol)];
    short8v ah2 = AS[cur][qcol * 16 + ((8 + kg) ^ qcol)];
    short8v ah3 = AS[cur][qcol * 16 + ((12 + kg) ^ qcol)];
    f32x4 acc = {0.f, 0.f, 0.f, 0.f};
    acc = __builtin_amdgcn_mfma_f32_16x16x32_bf16(ah0, bh0, acc, 0, 0, 0);
    acc = __builtin_amdgcn_mfma_f32_16x16x32_bf16(ah1, bh1, acc, 0, 0, 0);
    acc = __builtin_amdgcn_mfma_f32_16x16x32_bf16(ah2, bh2, acc, 0, 0, 0);
    acc = __builtin_amdgcn_mfma_f32_16x16x32_bf16(ah3, bh3, acc, 0, 0, 0);
    float4 hs = *(const float4*)&hsq[base + lt * 16 + kg * 4];
    float hsa[4] = {hs.x, hs.y, hs.z, hs.w};

    if (lt < 4) {
#pragma unroll
      for (int r = 0; r < 4; ++r) {
        float tv = acc[r] - hsa[r] + 512.0f;
        bd[lt * 4 + r] = (__float_as_uint(tv) & ~1023u) | (1023u - (unsigned)(lt * 4 + r));
      }
      if (lt == 3) {
        unsigned int m0 = umin3(bd[0], bd[1], bd[2]);
        m0 = umin3(m0, bd[3], bd[4]);
        m0 = umin3(m0, bd[5], bd[6]);
        m0 = umin2(m0, bd[7]);
        unsigned int m1 = umin3(bd[8], bd[9], bd[10]);
        m1 = umin3(m1, bd[11], bd[12]);
        m1 = umin3(m1, bd[13], bd[14]);
        m1 = umin2(m1, bd[15]);
        worst = umin2(m0, m1);
      }
    } else {
#pragma unroll
      for (int r = 0; r < 4; ++r) {
        float tv = acc[r] - hsa[r] + 512.0f;
        unsigned int key = (__float_as_uint(tv) & ~1023u) | (1023u - (unsigned)(lt * 4 + r));
        if (key > worst) {
#pragma unroll
          for (int i = 0; i < 16; ++i) bd[i] = (bd[i] == worst) ? key : bd[i];
          unsigned int n0_ = umin3(bd[0], bd[1], bd[2]);
          n0_ = umin3(n0_, bd[3], bd[4]);
          n0_ = umin3(n0_, bd[5], bd[6]);
          n0_ = umin2(n0_, bd[7]);
          unsigned int n1_ = umin3(bd[8], bd[9], bd[10]);
          n1_ = umin3(n1_, bd[11], bd[12]);
          n1_ = umin3(n1_, bd[13], bd[14]);
          n1_ = umin2(n1_, bd[15]);
          worst = umin2(n0_, n1_);
        }
      }
    }
    __syncthreads();
    cur ^= 1;
  }

#pragma unroll
  for (int i = 0; i < 16; ++i) mv[w][qcol][kg * 16 + i] = bd[i];
  __syncthreads();

  if (lane < 16) {
    unsigned int tb[16];
#pragma unroll
    for (int i = 0; i < 16; ++i) tb[i] = mv[w][lane][i];
    unsigned int w0 = umin3(tb[0], tb[1], tb[2]);
    w0 = umin3(w0, tb[3], tb[4]);
    w0 = umin3(w0, tb[5], tb[6]);
    w0 = umin2(w0, tb[7]);
    unsigned int w1 = umin3(tb[8], tb[9], tb[10]);
    w1 = umin3(w1, tb[11], tb[12]);
    w1 = umin3(w1, tb[13], tb[14]);
    w1 = umin2(w1, tb[15]);
    unsigned int wst = umin2(w0, w1);
    for (int j = 16; j < 64; ++j) {
      unsigned int v = mv[w][lane][j];
      if (v > wst) {
        bool done = false;
#pragma unroll
        for (int i = 0; i < 16; ++i) {
          bool m = (!done) && (tb[i] == wst);
          done = done || m;
          tb[i] = m ? v : tb[i];
        }
        unsigned int a0 = umin3(tb[0], tb[1], tb[2]);
        a0 = umin3(a0, tb[3], tb[4]);
        a0 = umin3(a0, tb[5], tb[6]);
        a0 = umin2(a0, tb[7]);
        unsigned int a1 = umin3(tb[8], tb[9], tb[10]);
        a1 = umin3(a1, tb[11], tb[12]);
        a1 = umin3(a1, tb[13], tb[14]);
        a1 = umin2(a1, tb[15]);
        wst = umin2(a0, a1);
      }
    }
    thr[base + qg * 64 + w * 16 + lane] = __uint_as_float(wst & ~1023u) - 0.5f;
  }
}

// ---------------------------------------------------------------------------
// Collect survivors (tv >= thr[q]): LDS-staged tiles + ballot-compaction into
// per-wave LDS list, then bucket into per-(query,half) global lists.
__launch_bounds__(256)
__global__ void k_collect2(const unsigned short* __restrict__ xhi,
                           const float* __restrict__ hsq,
                           const float* __restrict__ thr,
                           unsigned short* __restrict__ cand,
                           unsigned short* __restrict__ qcnt) {
  __shared__ short8v AS[2][256];          // 8 KB staging
  __shared__ unsigned int buf[4][WBUF];   // 24 KB
  __shared__ unsigned int qc[4][16];
  int bx = blockIdx.x;
  int b = bx >> 7, rest = bx & 127;
  int qg = rest >> 1, ht = rest & 1;
  int w = threadIdx.x >> 6, lane = threadIdx.x & 63;
  int qcol = lane & 15, kg = lane >> 4;
  int base = b * NN;
  int q = base + qg * 64 + w * 16 + qcol;

  const short8v* XH = (const short8v*)xhi;
  short8v bh0 = XH[(size_t)q * 16 + kg];
  short8v bh1 = XH[(size_t)q * 16 + 4 + kg];
  short8v bh2 = XH[(size_t)q * 16 + 8 + kg];
  short8v bh3 = XH[(size_t)q * 16 + 12 + kg];
  float myThr = thr[q];
  if (lane < 16) qc[w][lane] = 0;

  int snode = w * 4 + (lane >> 4);
  int sgran = (lane & 15) ^ (snode & 15);

  gload16(xhi + ((size_t)(base + (ht * 128) * 16 + snode)) * 128 + sgran * 8,
          &AS[0][w * 64]);
  __syncthreads();

  int wbase = 0;
  unsigned long long ltmask = (1ull << lane) - 1ull;
  int cur = 0;

#pragma unroll 1
  for (int lt = 0; lt < 128; ++lt) {
    int t = ht * 128 + lt;
    if (lt + 1 < 128)
      gload16(xhi + ((size_t)(base + (t + 1) * 16 + snode)) * 128 + sgran * 8,
              &AS[cur ^ 1][w * 64]);
    short8v ah0 = AS[cur][qcol * 16 + ((0 + kg) ^ qcol)];
    short8v ah1 = AS[cur][qcol * 16 + ((4 + kg) ^ qcol)];
    short8v ah2 = AS[cur][qcol * 16 + ((8 + kg) ^ qcol)];
    short8v ah3 = AS[cur][qcol * 16 + ((12 + kg) ^ qcol)];
    f32x4 acc = {0.f, 0.f, 0.f, 0.f};
    acc = __builtin_amdgcn_mfma_f32_16x16x32_bf16(ah0, bh0, acc, 0, 0, 0);
    acc = __builtin_amdgcn_mfma_f32_16x16x32_bf16(ah1, bh1, acc, 0, 0, 0);
    acc = __builtin_amdgcn_mfma_f32_16x16x32_bf16(ah2, bh2, acc, 0, 0, 0);
    acc = __builtin_amdgcn_mfma_f32_16x16x32_bf16(ah3, bh3, acc, 0, 0, 0);
    float4 hs = *(const float4*)&hsq[base + t * 16 + kg * 4];
    float hsa[4] = {hs.x, hs.y, hs.z, hs.w};
#pragma unroll
    for (int r = 0; r < 4; ++r) {
      float tv = acc[r] - hsa[r] + 512.0f;
      bool pass = tv >= myThr;
      unsigned long long mask = __ballot(pass);
      if (mask) {
        int pos = wbase + (int)__popcll(mask & ltmask);
        if (pass && pos < WBUF)
          buf[w][pos] = ((unsigned)qcol << 12) | (unsigned)(t * 16 + kg * 4 + r);
        wbase += (int)__popcll(mask);
      }
    }
    __syncthreads();
    cur ^= 1;
  }
  if (wbase > WBUF) wbase = WBUF;

  for (int i = lane; i < wbase; i += 64) {
    unsigned int e = buf[w][i];
    int ql = (int)(e >> 12);
    unsigned int slot = atomicAdd(&qc[w][ql], 1u);
    if (slot < CAPH)
      cand[(size_t)(base + qg * 64 + w * 16 + ql) * (2 * CAPH) + ht * CAPH + slot] =
          (unsigned short)(e & 0xfffu);
  }
  __syncthreads();

  if (lane < 16) {
    unsigned int c = qc[w][lane];
    if (c > CAPH) c = CAPH;
    qcnt[(size_t)(base + qg * 64 + w * 16 + lane) * 2 + ht] = (unsigned short)c;
  }
}

// ---------------------------------------------------------------------------
// Exact f32 rerank, 4-lane cooperative, 16 candidates in flight per pass:
// lane = (cand = lane>>2, part = lane&3); per phase each lane reads float4 at
// part*4 + ph*16 floats -> wave touches 16 rows x 64B contiguous per instr.
// Values parked in LDS, then R8-style (val desc, idx asc) selection.
__launch_bounds__(256)
__global__ void k_rerank(const float* __restrict__ xt, const float* __restrict__ hsq,
                         const unsigned short* __restrict__ cand,
                         const unsigned short* __restrict__ qcnt,
                         unsigned short* __restrict__ nbr) {
  __shared__ float pv[4][256];
  int w = threadIdx.x >> 6;
  int wq = blockIdx.x * 4 + w;
  int lane = threadIdx.x & 63;
  int b = wq >> 12;
  int base = b * NN;
  int n0 = qcnt[(size_t)wq * 2];
  int n1 = qcnt[(size_t)wq * 2 + 1];
  int nt = n0 + n1;                       // <= 256
  const float* qr = xt + (size_t)wq * CC;
  int cid = lane >> 2, part = lane & 3;

  // query chunks: phase ph covers floats ph*16 + part*4 .. +3
  float4 qv[8];
#pragma unroll
  for (int ph = 0; ph < 8; ++ph)
    qv[ph] = *(const float4*)&qr[ph * 16 + part * 4];

  int npass = (nt + 15) >> 4;
#pragma unroll 1
  for (int p = 0; p < npass; ++p) {
    int j = p * 16 + cid;
    bool valid = j < nt;
    int c = 0;
    if (valid)
      c = (j < n0) ? cand[(size_t)wq * (2 * CAPH) + j]
                   : cand[(size_t)wq * (2 * CAPH) + CAPH + (j - n0)];
    const float* cr = xt + (size_t)(base + c) * CC;
    float acc = 0.f;
#pragma unroll
    for (int ph = 0; ph < 8; ++ph) {
      float4 cv = *(const float4*)&cr[ph * 16 + part * 4];
      acc = fmaf(qv[ph].x, cv.x, acc);
      acc = fmaf(qv[ph].y, cv.y, acc);
      acc = fmaf(qv[ph].z, cv.z, acc);
      acc = fmaf(qv[ph].w, cv.w, acc);
    }
    acc += __shfl_xor(acc, 1, 64);
    acc += __shfl_xor(acc, 2, 64);
    if (part == 0)
      pv[w][p * 16 + cid] = valid ? (acc - hsq[base + c]) : -3.4e38f;
  }

  // selection over up to 256 values (4 slots per lane)
  float vs[4]; int is[4];
#pragma unroll
  for (int s = 0; s < 4; ++s) {
    int j = lane + s * 64;
    if (j < nt) {
      vs[s] = pv[w][j];
      is[s] = (j < n0) ? cand[(size_t)wq * (2 * CAPH) + j]
                       : cand[(size_t)wq * (2 * CAPH) + CAPH + (j - n0)];
    } else {
      vs[s] = -3.4e38f; is[s] = 0x7fffffff;
    }
  }

  unsigned short* o = nbr + (size_t)wq * KK;
  for (int s = 0; s < KK; ++s) {
    float bv = vs[0]; int bi_ = is[0];
#pragma unroll
    for (int t = 1; t < 4; ++t)
      if ((vs[t] > bv) || (vs[t] == bv && is[t] < bi_)) { bv = vs[t]; bi_ = is[t]; }
#pragma unroll
    for (int off = 1; off < 64; off <<= 1) {
      float ov = __shfl_xor(bv, off, 64);
      int oi = __shfl_xor(bi_, off, 64);
      bool take = (ov > bv) || (ov == bv && oi < bi_);
      bv = take ? ov : bv;
      bi_ = take ? oi : bi_;
    }
    if (lane == 0) o[s] = (unsigned short)bi_;
#pragma unroll
    for (int t = 0; t < 4; ++t)
      if (is[t] == bi_) { vs[t] = -3.4e38f; is[t] = 0x7fffffff; }
  }
}

// ---------------------------------------------------------------------------
// h = xt . W via 3-term split-bf16 MFMA (xhi*Whi + xhi*Wlo + xlo*Whi), bf16 out
__launch_bounds__(256)
__global__ void k_h2(const float* __restrict__ xt,
                     const unsigned short* __restrict__ Whi,
                     const unsigned short* __restrict__ Wlo,
                     unsigned short* __restrict__ hout) {
  int w = threadIdx.x >> 6, lane = threadIdx.x & 63;
  int r16 = lane & 15, kg = lane >> 4;
  int nd0 = blockIdx.x * 64 + w * 16;
  const float* arow = xt + (size_t)(nd0 + r16) * CC;
  short8v ahi[4], alo[4];
#pragma unroll
  for (int ks = 0; ks < 4; ++ks) {
    float4 f0 = *(const float4*)&arow[ks * 32 + kg * 8];
    float4 f1 = *(const float4*)&arow[ks * 32 + kg * 8 + 4];
    float fv[8] = {f0.x, f0.y, f0.z, f0.w, f1.x, f1.y, f1.z, f1.w};
    short8v hh_, ll_;
#pragma unroll
    for (int j = 0; j < 8; ++j) {
      unsigned short hb = f2bf(fv[j]);
      hh_[j] = (short)hb;
      ll_[j] = (short)f2bf(fv[j] - bf2f(hb));
    }
    ahi[ks] = hh_; alo[ks] = ll_;
  }
  const short8v* WH = (const short8v*)Whi;   // granule: hf*16 + ks*4 + kg
  const short8v* WL = (const short8v*)Wlo;
#pragma unroll 1
  for (int ct = 0; ct < 32; ++ct) {
    int hf = ct * 16 + r16;
    f32x4 acc = {0.f, 0.f, 0.f, 0.f};
#pragma unroll
    for (int ks = 0; ks < 4; ++ks) {
      short8v bh = WH[(size_t)hf * 16 + ks * 4 + kg];
      short8v bl = WL[(size_t)hf * 16 + ks * 4 + kg];
      acc = __builtin_amdgcn_mfma_f32_16x16x32_bf16(ahi[ks], bh, acc, 0, 0, 0);
      acc = __builtin_amdgcn_mfma_f32_16x16x32_bf16(ahi[ks], bl, acc, 0, 0, 0);
      acc = __builtin_amdgcn_mfma_f32_16x16x32_bf16(alo[ks], bh, acc, 0, 0, 0);
    }
#pragma unroll
    for (int r = 0; r < 4; ++r)
      hout[(size_t)(nd0 + kg * 4 + r) * HF + hf] = f2bf(acc[r]);
  }
}

// ---------------------------------------------------------------------------
// a_src/a_dst[b][n][h] = sum_f h[b][n][h][f] * att_{src,dst}[h][f]
__global__ void k_att(const unsigned short* __restrict__ h,
                      const float* __restrict__ att_src, const float* __restrict__ att_dst,
                      float* __restrict__ a_src, float* __restrict__ a_dst) {
  int gid = blockIdx.x * 256 + threadIdx.x;
  int wid = gid >> 6;            // node index b*N+n
  int lane = threadIdx.x & 63;
  uint4 v = ((const uint4*)(h + (size_t)wid * HF))[lane];
  float hv[8];
  hv[0] = bf2f(v.x & 0xffff); hv[1] = bf2f(v.x >> 16);
  hv[2] = bf2f(v.y & 0xffff); hv[3] = bf2f(v.y >> 16);
  hv[4] = bf2f(v.z & 0xffff); hv[5] = bf2f(v.z >> 16);
  hv[6] = bf2f(v.w & 0xffff); hv[7] = bf2f(v.w >> 16);
  int base = lane * 8;
  float s = 0.f, d = 0.f;
#pragma unroll
  for (int i = 0; i < 8; ++i) {
    s += hv[i] * att_src[base + i];
    d += hv[i] * att_dst[base + i];
  }
#pragma unroll
  for (int off = 1; off < 16; off <<= 1) {
    s += __shfl_xor(s, off, 64);
    d += __shfl_xor(d, off, 64);
  }
  if ((lane & 15) == 0) {
    int hh = lane >> 4;
    a_src[wid * HH + hh] = s;
    a_dst[wid * HH + hh] = d;
  }
}

// ---------------------------------------------------------------------------
// gather + softmax(k=16) + weighted sum + head-mean + bias + transpose store
__launch_bounds__(256)
__global__ void k_out(const unsigned short* __restrict__ h,
                      const unsigned short* __restrict__ nbr,
                      const float* __restrict__ a_src, const float* __restrict__ a_dst,
                      const float* __restrict__ bias, float* __restrict__ out) {
  __shared__ float Ot[FF][17];
  int b = blockIdx.x >> 8, nb = blockIdx.x & 255;
  int w = threadIdx.x >> 6, lane = threadIdx.x & 63;
  int hh = lane >> 4, jj = lane & 15;

  for (int t = 0; t < 4; ++t) {
    int nl = w * 4 + t;
    int node = b * NN + nb * 16 + nl;
    int mj = nbr[node * KK + jj];

    float e = a_src[((size_t)b * NN + mj) * HH + hh] + a_dst[(size_t)node * HH + hh];
    e = e >= 0.f ? e : 0.2f * e;
    float m = e;
#pragma unroll
    for (int off = 1; off < 16; off <<= 1) m = fmaxf(m, __shfl_xor(m, off, 64));
    float p = expf(e - m);
    float sum = p;
#pragma unroll
    for (int off = 1; off < 16; off <<= 1) sum += __shfl_xor(sum, off, 64);
    float alpha = p / sum;

    float acc[8];
#pragma unroll
    for (int i = 0; i < 8; ++i) acc[i] = 0.f;

#pragma unroll
    for (int j = 0; j < 16; ++j) {
      float aj = __shfl(alpha, (hh << 4) | j, 64);
      int m2 = __shfl(mj, j, 64);
      uint4 v = ((const uint4*)(h + (size_t)(b * NN + m2) * HF))[lane];
      acc[0] += aj * bf2f(v.x & 0xffff); acc[1] += aj * bf2f(v.x >> 16);
      acc[2] += aj * bf2f(v.y & 0xffff); acc[3] += aj * bf2f(v.y >> 16);
      acc[4] += aj * bf2f(v.z & 0xffff); acc[5] += aj * bf2f(v.z >> 16);
      acc[6] += aj * bf2f(v.w & 0xffff); acc[7] += aj * bf2f(v.w >> 16);
    }

#pragma unroll
    for (int i = 0; i < 8; ++i) {
      acc[i] += __shfl_xor(acc[i], 16, 64);
      acc[i] += __shfl_xor(acc[i], 32, 64);
    }
    if (hh == 0) {
#pragma unroll
      for (int i = 0; i < 8; ++i) Ot[jj * 8 + i][nl] = acc[i] * 0.25f;
    }
  }
  __syncthreads();

#pragma unroll
  for (int it = 0; it < 8; ++it) {
    int idx = it * 256 + threadIdx.x;
    int f = idx >> 4, nl = idx & 15;
    out[((size_t)b * FF + f) * NN + nb * 16 + nl] = Ot[f][nl] + bias[f];
  }
}

// ---------------------------------------------------------------------------
extern "C" void kernel_launch(void* const* d_in, const int* in_sizes, int n_in,
                              void* d_out, int out_size, void* d_ws, size_t ws_size,
                              hipStream_t stream) {
  const float* x       = (const float*)d_in[0];
  const float* W       = (const float*)d_in[1];
  const float* att_src = (const float*)d_in[2];
  const float* att_dst = (const float*)d_in[3];
  const float* bias    = (const float*)d_in[4];

  char* ws = (char*)d_ws;
  // Lifetime-aliased layout; all sizes verified numerically (same as R8/R9):
  //   [0        ,16777216): xt    f32 32768*128*4 = 16,777,216 — split..rerank,h2
  //   [16777216 ,25165824): xhi   bf16 32768*128*2 = 8,388,608 — split..collect2
  //   [25165824 ,41943040): cand  u16 32768*256*2 = 16,777,216 — collect2..rerank
  //   [16777216 ,50331648): h     bf16 32768*512*2 = 33,554,432 — k_h2 AFTER rerank
  //   [50331648 ,51380224): nbr   u16 32768*16*2 = 1,048,576   — rerank..out
  //   [51380224 ,51511296): qcnt  u16 32768*2*2 = 131,072      — collect2..rerank
  //   [51511296 ,51642368): thr   f32 32768*4 = 131,072        — tauscan..collect2
  //   [51642368 ,51773440): hsq   f32 32768*4 = 131,072        — split..rerank
  //   [51773440 ,52297728): a_src f32 524,288 (aliased early by Whi+Wlo 2*131,072)
  //   [52297728 ,52822016): a_dst f32 524,288
  // total 52,822,016 B (proven envelope)
  float* xt            = (float*)ws;
  unsigned short* xhi  = (unsigned short*)(ws + 16777216);
  unsigned short* cand = (unsigned short*)(ws + 25165824);
  unsigned short* h    = (unsigned short*)(ws + 16777216);
  unsigned short* nbr  = (unsigned short*)(ws + 50331648);
  unsigned short* qcnt = (unsigned short*)(ws + 51380224);
  float* thr   = (float*)(ws + 51511296);
  float* hsq   = (float*)(ws + 51642368);
  float* a_src = (float*)(ws + 51773440);
  unsigned short* Whi  = (unsigned short*)(ws + 51773440);
  unsigned short* Wlo  = (unsigned short*)(ws + 51773440 + 131072);
  float* a_dst = (float*)(ws + 52297728);

  float* out = (float*)d_out;

  k_split   <<<BB * (NN / 64), 256, 0, stream>>>(x, xt, xhi, hsq);
  k_wpack   <<<HF * CC / 256, 256, 0, stream>>>(W, Whi, Wlo);
  k_tauscan <<<BB * 64, 256, 0, stream>>>(xhi, hsq, thr);
  k_collect2<<<BB * 64 * 2, 256, 0, stream>>>(xhi, hsq, thr, cand, qcnt);
  k_rerank  <<<BB * NN / 4, 256, 0, stream>>>(xt, hsq, cand, qcnt, nbr);
  k_h2      <<<BB * NN / 64, 256, 0, stream>>>(xt, Whi, Wlo, h);
  k_att     <<<BB * NN / 4, 256, 0, stream>>>(h, att_src, att_dst, a_src, a_dst);
  k_out     <<<BB * (NN / 16), 256, 0, stream>>>(h, nbr, a_src, a_dst, bias, out);
}

// Round 11
// 444.623 us; speedup vs baseline: 1.8469x; 1.0572x over previous
//
#include <hip/hip_runtime.h>
#include <hip/hip_bf16.h>

#define BB 8
#define CC 128
#define NN 4096
#define HH 4
#define FF 128
#define KK 16
#define HF 512      // H*F
#define CAPH 128    // survivor capacity per query per half (stride 256 total)
#define WBUF 1536   // per-wave compaction buffer entries (20 sigma)

typedef __attribute__((ext_vector_type(8))) short short8v;
typedef __attribute__((ext_vector_type(8))) unsigned short ushort8v;
typedef __attribute__((ext_vector_type(4))) float f32x4;

__device__ __forceinline__ float bf2f(unsigned int u) {
  return __uint_as_float(u << 16);
}

__device__ __forceinline__ unsigned short f2bf(float f) {
  unsigned int u = __float_as_uint(f);
  unsigned int lsb = (u >> 16) & 1u;
  u += 0x7fffu + lsb;                 // RTNE
  return (unsigned short)(u >> 16);
}

__device__ __forceinline__ unsigned int umin2(unsigned int a, unsigned int b) {
  return a < b ? a : b;
}
__device__ __forceinline__ unsigned int umin3(unsigned int a, unsigned int b, unsigned int c) {
  return umin2(umin2(a, b), c);
}

// async global->LDS, 16B per lane; lds base must be wave-uniform
__device__ __forceinline__ void gload16(const void* gsrc, void* ldst) {
  __builtin_amdgcn_global_load_lds(
      (const __attribute__((address_space(1))) unsigned int*)gsrc,
      (__attribute__((address_space(3))) unsigned int*)ldst, 16, 0, 0);
}

// ---------------------------------------------------------------------------
// x[b][c][n] -> xt[b][n][c] (f32), xhi[b][n][c] (bf16), hsq[b][n] = 0.5*|x|^2
__launch_bounds__(256)
__global__ void k_split(const float* __restrict__ x,
                        float* __restrict__ xt,
                        unsigned short* __restrict__ xhi,
                        float* __restrict__ hsq) {
  __shared__ float Ls[CC][65];
  int b = blockIdx.x >> 6, nb = blockIdx.x & 63;
  int n0 = nb * 64;
  int tid = threadIdx.x;
  const float* xb = x + (size_t)b * CC * NN;

  for (int i = tid; i < CC * 64; i += 256) {
    int c = i >> 6, nl = i & 63;
    Ls[c][nl] = xb[(size_t)c * NN + n0 + nl];
  }
  __syncthreads();

  int n = tid >> 2, part = tid & 3;     // 64 n x 4 parts (32 c each)
  int node = b * NN + n0 + n;
  float sum = 0.f;
#pragma unroll
  for (int g = 0; g < 4; ++g) {
    float v[8];
    ushort8v ph;
#pragma unroll
    for (int j = 0; j < 8; ++j) {
      int c = part * 32 + g * 8 + j;
      v[j] = Ls[c][n];
      ph[j] = f2bf(v[j]);
      sum += v[j] * v[j];
    }
    float4 f0 = {v[0], v[1], v[2], v[3]};
    float4 f1 = {v[4], v[5], v[6], v[7]};
    *(float4*)&xt[(size_t)node * CC + part * 32 + g * 8] = f0;
    *(float4*)&xt[(size_t)node * CC + part * 32 + g * 8 + 4] = f1;
    *(ushort8v*)&xhi[(size_t)node * CC + part * 32 + g * 8] = ph;
  }
  sum += __shfl_xor(sum, 1, 64);
  sum += __shfl_xor(sum, 2, 64);
  if (part == 0) hsq[node] = 0.5f * sum;
}

// ---------------------------------------------------------------------------
// Pack W[c][hf] f32 -> Whi/Wlo[hf][c] bf16
__global__ void k_wpack(const float* __restrict__ W,
                        unsigned short* __restrict__ Whi,
                        unsigned short* __restrict__ Wlo) {
  int i = blockIdx.x * 256 + threadIdx.x;   // over 512*128
  int hf = i >> 7, c = i & 127;
  float v = W[(size_t)c * HF + hf];
  unsigned short hb = f2bf(v);
  Whi[i] = hb;
  Wlo[i] = f2bf(v - bf2f(hb));
}

// ---------------------------------------------------------------------------
// tau scan over candidates 0..1023 (subset): LDS-staged tiles (double-buffered
// global_load_lds, XOR-preswizzled source, XOR-swizzled read). Per-lane insert
// top-16, merge 4 lanes -> 16th-best key; thr[q] = floor16(key) - 0.5.
__launch_bounds__(256)
__global__ void k_tauscan(const unsigned short* __restrict__ xhi,
                          const float* __restrict__ hsq,
                          float* __restrict__ thr) {
  __shared__ short8v AS[2][256];           // 8 KB staging (16 nodes x 16 granules)
  __shared__ unsigned int mv[4][16][64];   // 16 KB
  int b = blockIdx.x >> 6, qg = blockIdx.x & 63;
  int w = threadIdx.x >> 6, lane = threadIdx.x & 63;
  int qcol = lane & 15, kg = lane >> 4;
  int base = b * NN;
  int q = base + qg * 64 + w * 16 + qcol;

  const short8v* XH = (const short8v*)xhi;   // granules: node*16 + ks*4 + kg
  short8v bh0 = XH[(size_t)q * 16 + kg];
  short8v bh1 = XH[(size_t)q * 16 + 4 + kg];
  short8v bh2 = XH[(size_t)q * 16 + 8 + kg];
  short8v bh3 = XH[(size_t)q * 16 + 12 + kg];

  // staging geometry: this wave fills nodes 4w..4w+3; LDS linear slot
  // (node, j) holds global granule (j ^ node) of node  [involution]
  int snode = w * 4 + (lane >> 4);
  int sgran = (lane & 15) ^ (snode & 15);

  gload16(xhi + ((size_t)(base + snode)) * 128 + sgran * 8, &AS[0][w * 64]);
  __syncthreads();

  unsigned int bd[16];
  unsigned int worst = 0;
  int cur = 0;

#pragma unroll 1
  for (int lt = 0; lt < 64; ++lt) {
    if (lt + 1 < 64)
      gload16(xhi + ((size_t)(base + (lt + 1) * 16 + snode)) * 128 + sgran * 8,
              &AS[cur ^ 1][w * 64]);
    short8v ah0 = AS[cur][qcol * 16 + ((0 + kg) ^ qcol)];
    short8v ah1 = AS[cur][qcol * 16 + ((4 + kg) ^ qcol)];
    short8v ah2 = AS[cur][qcol * 16 + ((8 + kg) ^ qcol)];
    short8v ah3 = AS[cur][qcol * 16 + ((12 + kg) ^ qcol)];
    f32x4 acc = {0.f, 0.f, 0.f, 0.f};
    acc = __builtin_amdgcn_mfma_f32_16x16x32_bf16(ah0, bh0, acc, 0, 0, 0);
    acc = __builtin_amdgcn_mfma_f32_16x16x32_bf16(ah1, bh1, acc, 0, 0, 0);
    acc = __builtin_amdgcn_mfma_f32_16x16x32_bf16(ah2, bh2, acc, 0, 0, 0);
    acc = __builtin_amdgcn_mfma_f32_16x16x32_bf16(ah3, bh3, acc, 0, 0, 0);
    float4 hs = *(const float4*)&hsq[base + lt * 16 + kg * 4];
    float hsa[4] = {hs.x, hs.y, hs.z, hs.w};

    if (lt < 4) {
#pragma unroll
      for (int r = 0; r < 4; ++r) {
        float tv = acc[r] - hsa[r] + 512.0f;
        bd[lt * 4 + r] = (__float_as_uint(tv) & ~1023u) | (1023u - (unsigned)(lt * 4 + r));
      }
      if (lt == 3) {
        unsigned int m0 = umin3(bd[0], bd[1], bd[2]);
        m0 = umin3(m0, bd[3], bd[4]);
        m0 = umin3(m0, bd[5], bd[6]);
        m0 = umin2(m0, bd[7]);
        unsigned int m1 = umin3(bd[8], bd[9], bd[10]);
        m1 = umin3(m1, bd[11], bd[12]);
        m1 = umin3(m1, bd[13], bd[14]);
        m1 = umin2(m1, bd[15]);
        worst = umin2(m0, m1);
      }
    } else {
#pragma unroll
      for (int r = 0; r < 4; ++r) {
        float tv = acc[r] - hsa[r] + 512.0f;
        unsigned int key = (__float_as_uint(tv) & ~1023u) | (1023u - (unsigned)(lt * 4 + r));
        if (key > worst) {
#pragma unroll
          for (int i = 0; i < 16; ++i) bd[i] = (bd[i] == worst) ? key : bd[i];
          unsigned int n0_ = umin3(bd[0], bd[1], bd[2]);
          n0_ = umin3(n0_, bd[3], bd[4]);
          n0_ = umin3(n0_, bd[5], bd[6]);
          n0_ = umin2(n0_, bd[7]);
          unsigned int n1_ = umin3(bd[8], bd[9], bd[10]);
          n1_ = umin3(n1_, bd[11], bd[12]);
          n1_ = umin3(n1_, bd[13], bd[14]);
          n1_ = umin2(n1_, bd[15]);
          worst = umin2(n0_, n1_);
        }
      }
    }
    __syncthreads();
    cur ^= 1;
  }

#pragma unroll
  for (int i = 0; i < 16; ++i) mv[w][qcol][kg * 16 + i] = bd[i];
  __syncthreads();

  if (lane < 16) {
    unsigned int tb[16];
#pragma unroll
    for (int i = 0; i < 16; ++i) tb[i] = mv[w][lane][i];
    unsigned int w0 = umin3(tb[0], tb[1], tb[2]);
    w0 = umin3(w0, tb[3], tb[4]);
    w0 = umin3(w0, tb[5], tb[6]);
    w0 = umin2(w0, tb[7]);
    unsigned int w1 = umin3(tb[8], tb[9], tb[10]);
    w1 = umin3(w1, tb[11], tb[12]);
    w1 = umin3(w1, tb[13], tb[14]);
    w1 = umin2(w1, tb[15]);
    unsigned int wst = umin2(w0, w1);
    for (int j = 16; j < 64; ++j) {
      unsigned int v = mv[w][lane][j];
      if (v > wst) {
        bool done = false;
#pragma unroll
        for (int i = 0; i < 16; ++i) {
          bool m = (!done) && (tb[i] == wst);
          done = done || m;
          tb[i] = m ? v : tb[i];
        }
        unsigned int a0 = umin3(tb[0], tb[1], tb[2]);
        a0 = umin3(a0, tb[3], tb[4]);
        a0 = umin3(a0, tb[5], tb[6]);
        a0 = umin2(a0, tb[7]);
        unsigned int a1 = umin3(tb[8], tb[9], tb[10]);
        a1 = umin3(a1, tb[11], tb[12]);
        a1 = umin3(a1, tb[13], tb[14]);
        a1 = umin2(a1, tb[15]);
        wst = umin2(a0, a1);
      }
    }
    thr[base + qg * 64 + w * 16 + lane] = __uint_as_float(wst & ~1023u) - 0.5f;
  }
}

// ---------------------------------------------------------------------------
// Collect survivors (tv >= thr[q]): LDS-staged tiles + ballot-compaction into
// per-wave LDS list, then bucket into per-(query,half) global lists.
__launch_bounds__(256)
__global__ void k_collect2(const unsigned short* __restrict__ xhi,
                           const float* __restrict__ hsq,
                           const float* __restrict__ thr,
                           unsigned short* __restrict__ cand,
                           unsigned short* __restrict__ qcnt) {
  __shared__ short8v AS[2][256];          // 8 KB staging
  __shared__ unsigned int buf[4][WBUF];   // 24 KB
  __shared__ unsigned int qc[4][16];
  int bx = blockIdx.x;
  int b = bx >> 7, rest = bx & 127;
  int qg = rest >> 1, ht = rest & 1;
  int w = threadIdx.x >> 6, lane = threadIdx.x & 63;
  int qcol = lane & 15, kg = lane >> 4;
  int base = b * NN;
  int q = base + qg * 64 + w * 16 + qcol;

  const short8v* XH = (const short8v*)xhi;
  short8v bh0 = XH[(size_t)q * 16 + kg];
  short8v bh1 = XH[(size_t)q * 16 + 4 + kg];
  short8v bh2 = XH[(size_t)q * 16 + 8 + kg];
  short8v bh3 = XH[(size_t)q * 16 + 12 + kg];
  float myThr = thr[q];
  if (lane < 16) qc[w][lane] = 0;

  int snode = w * 4 + (lane >> 4);
  int sgran = (lane & 15) ^ (snode & 15);

  gload16(xhi + ((size_t)(base + (ht * 128) * 16 + snode)) * 128 + sgran * 8,
          &AS[0][w * 64]);
  __syncthreads();

  int wbase = 0;
  unsigned long long ltmask = (1ull << lane) - 1ull;
  int cur = 0;

#pragma unroll 1
  for (int lt = 0; lt < 128; ++lt) {
    int t = ht * 128 + lt;
    if (lt + 1 < 128)
      gload16(xhi + ((size_t)(base + (t + 1) * 16 + snode)) * 128 + sgran * 8,
              &AS[cur ^ 1][w * 64]);
    short8v ah0 = AS[cur][qcol * 16 + ((0 + kg) ^ qcol)];
    short8v ah1 = AS[cur][qcol * 16 + ((4 + kg) ^ qcol)];
    short8v ah2 = AS[cur][qcol * 16 + ((8 + kg) ^ qcol)];
    short8v ah3 = AS[cur][qcol * 16 + ((12 + kg) ^ qcol)];
    f32x4 acc = {0.f, 0.f, 0.f, 0.f};
    acc = __builtin_amdgcn_mfma_f32_16x16x32_bf16(ah0, bh0, acc, 0, 0, 0);
    acc = __builtin_amdgcn_mfma_f32_16x16x32_bf16(ah1, bh1, acc, 0, 0, 0);
    acc = __builtin_amdgcn_mfma_f32_16x16x32_bf16(ah2, bh2, acc, 0, 0, 0);
    acc = __builtin_amdgcn_mfma_f32_16x16x32_bf16(ah3, bh3, acc, 0, 0, 0);
    float4 hs = *(const float4*)&hsq[base + t * 16 + kg * 4];
    float hsa[4] = {hs.x, hs.y, hs.z, hs.w};
#pragma unroll
    for (int r = 0; r < 4; ++r) {
      float tv = acc[r] - hsa[r] + 512.0f;
      bool pass = tv >= myThr;
      unsigned long long mask = __ballot(pass);
      if (mask) {
        int pos = wbase + (int)__popcll(mask & ltmask);
        if (pass && pos < WBUF)
          buf[w][pos] = ((unsigned)qcol << 12) | (unsigned)(t * 16 + kg * 4 + r);
        wbase += (int)__popcll(mask);
      }
    }
    __syncthreads();
    cur ^= 1;
  }
  if (wbase > WBUF) wbase = WBUF;

  for (int i = lane; i < wbase; i += 64) {
    unsigned int e = buf[w][i];
    int ql = (int)(e >> 12);
    unsigned int slot = atomicAdd(&qc[w][ql], 1u);
    if (slot < CAPH)
      cand[(size_t)(base + qg * 64 + w * 16 + ql) * (2 * CAPH) + ht * CAPH + slot] =
          (unsigned short)(e & 0xfffu);
  }
  __syncthreads();

  if (lane < 16) {
    unsigned int c = qc[w][lane];
    if (c > CAPH) c = CAPH;
    qcnt[(size_t)(base + qg * 64 + w * 16 + lane) * 2 + ht] = (unsigned short)c;
  }
}

// ---------------------------------------------------------------------------
// Exact f32 rerank, 8-lane cooperative, 8 candidates in flight per pass:
// lane = (cand = lane>>3, part = lane&7); per phase each lane reads float4 at
// ph*32 + part*4 floats -> wave touches 8 rows x 128B contiguous per instr
// (8 line-transactions vs 16 in the 4-lane version). Values parked in LDS,
// then (val desc, idx asc) selection as before.
__launch_bounds__(256)
__global__ void k_rerank(const float* __restrict__ xt, const float* __restrict__ hsq,
                         const unsigned short* __restrict__ cand,
                         const unsigned short* __restrict__ qcnt,
                         unsigned short* __restrict__ nbr) {
  __shared__ float pv[4][256];
  int w = threadIdx.x >> 6;
  int wq = blockIdx.x * 4 + w;
  int lane = threadIdx.x & 63;
  int b = wq >> 12;
  int base = b * NN;
  int n0 = qcnt[(size_t)wq * 2];
  int n1 = qcnt[(size_t)wq * 2 + 1];
  int nt = n0 + n1;                       // <= 256
  const float* qr = xt + (size_t)wq * CC;
  int cid = lane >> 3, part = lane & 7;

  // query chunks: phase ph covers floats ph*32 + part*4 .. +3
  float4 qv[4];
#pragma unroll
  for (int ph = 0; ph < 4; ++ph)
    qv[ph] = *(const float4*)&qr[ph * 32 + part * 4];

  int npass = (nt + 7) >> 3;
#pragma unroll 1
  for (int p = 0; p < npass; ++p) {
    int j = p * 8 + cid;
    bool valid = j < nt;
    int c = 0;
    if (valid)
      c = (j < n0) ? cand[(size_t)wq * (2 * CAPH) + j]
                   : cand[(size_t)wq * (2 * CAPH) + CAPH + (j - n0)];
    const float* cr = xt + (size_t)(base + c) * CC;
    float acc = 0.f;
#pragma unroll
    for (int ph = 0; ph < 4; ++ph) {
      float4 cv = *(const float4*)&cr[ph * 32 + part * 4];
      acc = fmaf(qv[ph].x, cv.x, acc);
      acc = fmaf(qv[ph].y, cv.y, acc);
      acc = fmaf(qv[ph].z, cv.z, acc);
      acc = fmaf(qv[ph].w, cv.w, acc);
    }
    acc += __shfl_xor(acc, 1, 64);
    acc += __shfl_xor(acc, 2, 64);
    acc += __shfl_xor(acc, 4, 64);
    if (part == 0)
      pv[w][p * 8 + cid] = valid ? (acc - hsq[base + c]) : -3.4e38f;
  }

  // selection over up to 256 values (4 slots per lane)
  float vs[4]; int is[4];
#pragma unroll
  for (int s = 0; s < 4; ++s) {
    int j = lane + s * 64;
    if (j < nt) {
      vs[s] = pv[w][j];
      is[s] = (j < n0) ? cand[(size_t)wq * (2 * CAPH) + j]
                       : cand[(size_t)wq * (2 * CAPH) + CAPH + (j - n0)];
    } else {
      vs[s] = -3.4e38f; is[s] = 0x7fffffff;
    }
  }

  unsigned short* o = nbr + (size_t)wq * KK;
  for (int s = 0; s < KK; ++s) {
    float bv = vs[0]; int bi_ = is[0];
#pragma unroll
    for (int t = 1; t < 4; ++t)
      if ((vs[t] > bv) || (vs[t] == bv && is[t] < bi_)) { bv = vs[t]; bi_ = is[t]; }
#pragma unroll
    for (int off = 1; off < 64; off <<= 1) {
      float ov = __shfl_xor(bv, off, 64);
      int oi = __shfl_xor(bi_, off, 64);
      bool take = (ov > bv) || (ov == bv && oi < bi_);
      bv = take ? ov : bv;
      bi_ = take ? oi : bi_;
    }
    if (lane == 0) o[s] = (unsigned short)bi_;
#pragma unroll
    for (int t = 0; t < 4; ++t)
      if (is[t] == bi_) { vs[t] = -3.4e38f; is[t] = 0x7fffffff; }
  }
}

// ---------------------------------------------------------------------------
// h = xt . W via 3-term split-bf16 MFMA (xhi*Whi + xhi*Wlo + xlo*Whi), bf16 out
__launch_bounds__(256)
__global__ void k_h2(const float* __restrict__ xt,
                     const unsigned short* __restrict__ Whi,
                     const unsigned short* __restrict__ Wlo,
                     unsigned short* __restrict__ hout) {
  int w = threadIdx.x >> 6, lane = threadIdx.x & 63;
  int r16 = lane & 15, kg = lane >> 4;
  int nd0 = blockIdx.x * 64 + w * 16;
  const float* arow = xt + (size_t)(nd0 + r16) * CC;
  short8v ahi[4], alo[4];
#pragma unroll
  for (int ks = 0; ks < 4; ++ks) {
    float4 f0 = *(const float4*)&arow[ks * 32 + kg * 8];
    float4 f1 = *(const float4*)&arow[ks * 32 + kg * 8 + 4];
    float fv[8] = {f0.x, f0.y, f0.z, f0.w, f1.x, f1.y, f1.z, f1.w};
    short8v hh_, ll_;
#pragma unroll
    for (int j = 0; j < 8; ++j) {
      unsigned short hb = f2bf(fv[j]);
      hh_[j] = (short)hb;
      ll_[j] = (short)f2bf(fv[j] - bf2f(hb));
    }
    ahi[ks] = hh_; alo[ks] = ll_;
  }
  const short8v* WH = (const short8v*)Whi;   // granule: hf*16 + ks*4 + kg
  const short8v* WL = (const short8v*)Wlo;
#pragma unroll 1
  for (int ct = 0; ct < 32; ++ct) {
    int hf = ct * 16 + r16;
    f32x4 acc = {0.f, 0.f, 0.f, 0.f};
#pragma unroll
    for (int ks = 0; ks < 4; ++ks) {
      short8v bh = WH[(size_t)hf * 16 + ks * 4 + kg];
      short8v bl = WL[(size_t)hf * 16 + ks * 4 + kg];
      acc = __builtin_amdgcn_mfma_f32_16x16x32_bf16(ahi[ks], bh, acc, 0, 0, 0);
      acc = __builtin_amdgcn_mfma_f32_16x16x32_bf16(ahi[ks], bl, acc, 0, 0, 0);
      acc = __builtin_amdgcn_mfma_f32_16x16x32_bf16(alo[ks], bh, acc, 0, 0, 0);
    }
#pragma unroll
    for (int r = 0; r < 4; ++r)
      hout[(size_t)(nd0 + kg * 4 + r) * HF + hf] = f2bf(acc[r]);
  }
}

// ---------------------------------------------------------------------------
// a_src/a_dst[b][n][h] = sum_f h[b][n][h][f] * att_{src,dst}[h][f]
__global__ void k_att(const unsigned short* __restrict__ h,
                      const float* __restrict__ att_src, const float* __restrict__ att_dst,
                      float* __restrict__ a_src, float* __restrict__ a_dst) {
  int gid = blockIdx.x * 256 + threadIdx.x;
  int wid = gid >> 6;            // node index b*N+n
  int lane = threadIdx.x & 63;
  uint4 v = ((const uint4*)(h + (size_t)wid * HF))[lane];
  float hv[8];
  hv[0] = bf2f(v.x & 0xffff); hv[1] = bf2f(v.x >> 16);
  hv[2] = bf2f(v.y & 0xffff); hv[3] = bf2f(v.y >> 16);
  hv[4] = bf2f(v.z & 0xffff); hv[5] = bf2f(v.z >> 16);
  hv[6] = bf2f(v.w & 0xffff); hv[7] = bf2f(v.w >> 16);
  int base = lane * 8;
  float s = 0.f, d = 0.f;
#pragma unroll
  for (int i = 0; i < 8; ++i) {
    s += hv[i] * att_src[base + i];
    d += hv[i] * att_dst[base + i];
  }
#pragma unroll
  for (int off = 1; off < 16; off <<= 1) {
    s += __shfl_xor(s, off, 64);
    d += __shfl_xor(d, off, 64);
  }
  if ((lane & 15) == 0) {
    int hh = lane >> 4;
    a_src[wid * HH + hh] = s;
    a_dst[wid * HH + hh] = d;
  }
}

// ---------------------------------------------------------------------------
// gather + softmax(k=16) + weighted sum + head-mean + bias + transpose store
__launch_bounds__(256)
__global__ void k_out(const unsigned short* __restrict__ h,
                      const unsigned short* __restrict__ nbr,
                      const float* __restrict__ a_src, const float* __restrict__ a_dst,
                      const float* __restrict__ bias, float* __restrict__ out) {
  __shared__ float Ot[FF][17];
  int b = blockIdx.x >> 8, nb = blockIdx.x & 255;
  int w = threadIdx.x >> 6, lane = threadIdx.x & 63;
  int hh = lane >> 4, jj = lane & 15;

  for (int t = 0; t < 4; ++t) {
    int nl = w * 4 + t;
    int node = b * NN + nb * 16 + nl;
    int mj = nbr[node * KK + jj];

    float e = a_src[((size_t)b * NN + mj) * HH + hh] + a_dst[(size_t)node * HH + hh];
    e = e >= 0.f ? e : 0.2f * e;
    float m = e;
#pragma unroll
    for (int off = 1; off < 16; off <<= 1) m = fmaxf(m, __shfl_xor(m, off, 64));
    float p = expf(e - m);
    float sum = p;
#pragma unroll
    for (int off = 1; off < 16; off <<= 1) sum += __shfl_xor(sum, off, 64);
    float alpha = p / sum;

    float acc[8];
#pragma unroll
    for (int i = 0; i < 8; ++i) acc[i] = 0.f;

#pragma unroll
    for (int j = 0; j < 16; ++j) {
      float aj = __shfl(alpha, (hh << 4) | j, 64);
      int m2 = __shfl(mj, j, 64);
      uint4 v = ((const uint4*)(h + (size_t)(b * NN + m2) * HF))[lane];
      acc[0] += aj * bf2f(v.x & 0xffff); acc[1] += aj * bf2f(v.x >> 16);
      acc[2] += aj * bf2f(v.y & 0xffff); acc[3] += aj * bf2f(v.y >> 16);
      acc[4] += aj * bf2f(v.z & 0xffff); acc[5] += aj * bf2f(v.z >> 16);
      acc[6] += aj * bf2f(v.w & 0xffff); acc[7] += aj * bf2f(v.w >> 16);
    }

#pragma unroll
    for (int i = 0; i < 8; ++i) {
      acc[i] += __shfl_xor(acc[i], 16, 64);
      acc[i] += __shfl_xor(acc[i], 32, 64);
    }
    if (hh == 0) {
#pragma unroll
      for (int i = 0; i < 8; ++i) Ot[jj * 8 + i][nl] = acc[i] * 0.25f;
    }
  }
  __syncthreads();

#pragma unroll
  for (int it = 0; it < 8; ++it) {
    int idx = it * 256 + threadIdx.x;
    int f = idx >> 4, nl = idx & 15;
    out[((size_t)b * FF + f) * NN + nb * 16 + nl] = Ot[f][nl] + bias[f];
  }
}

// ---------------------------------------------------------------------------
extern "C" void kernel_launch(void* const* d_in, const int* in_sizes, int n_in,
                              void* d_out, int out_size, void* d_ws, size_t ws_size,
                              hipStream_t stream) {
  const float* x       = (const float*)d_in[0];
  const float* W       = (const float*)d_in[1];
  const float* att_src = (const float*)d_in[2];
  const float* att_dst = (const float*)d_in[3];
  const float* bias    = (const float*)d_in[4];

  char* ws = (char*)d_ws;
  // Lifetime-aliased layout; all sizes verified numerically (same as R8-R10):
  //   [0        ,16777216): xt    f32 32768*128*4 = 16,777,216 — split..rerank,h2
  //   [16777216 ,25165824): xhi   bf16 32768*128*2 = 8,388,608 — split..collect2
  //   [25165824 ,41943040): cand  u16 32768*256*2 = 16,777,216 — collect2..rerank
  //   [16777216 ,50331648): h     bf16 32768*512*2 = 33,554,432 — k_h2 AFTER rerank
  //   [50331648 ,51380224): nbr   u16 32768*16*2 = 1,048,576   — rerank..out
  //   [51380224 ,51511296): qcnt  u16 32768*2*2 = 131,072      — collect2..rerank
  //   [51511296 ,51642368): thr   f32 32768*4 = 131,072        — tauscan..collect2
  //   [51642368 ,51773440): hsq   f32 32768*4 = 131,072        — split..rerank
  //   [51773440 ,52297728): a_src f32 524,288 (aliased early by Whi+Wlo 2*131,072)
  //   [52297728 ,52822016): a_dst f32 524,288
  // total 52,822,016 B (proven envelope)
  float* xt            = (float*)ws;
  unsigned short* xhi  = (unsigned short*)(ws + 16777216);
  unsigned short* cand = (unsigned short*)(ws + 25165824);
  unsigned short* h    = (unsigned short*)(ws + 16777216);
  unsigned short* nbr  = (unsigned short*)(ws + 50331648);
  unsigned short* qcnt = (unsigned short*)(ws + 51380224);
  float* thr   = (float*)(ws + 51511296);
  float* hsq   = (float*)(ws + 51642368);
  float* a_src = (float*)(ws + 51773440);
  unsigned short* Whi  = (unsigned short*)(ws + 51773440);
  unsigned short* Wlo  = (unsigned short*)(ws + 51773440 + 131072);
  float* a_dst = (float*)(ws + 52297728);

  float* out = (float*)d_out;

  k_split   <<<BB * (NN / 64), 256, 0, stream>>>(x, xt, xhi, hsq);
  k_wpack   <<<HF * CC / 256, 256, 0, stream>>>(W, Whi, Wlo);
  k_tauscan <<<BB * 64, 256, 0, stream>>>(xhi, hsq, thr);
  k_collect2<<<BB * 64 * 2, 256, 0, stream>>>(xhi, hsq, thr, cand, qcnt);
  k_rerank  <<<BB * NN / 4, 256, 0, stream>>>(xt, hsq, cand, qcnt, nbr);
  k_h2      <<<BB * NN / 64, 256, 0, stream>>>(xt, Whi, Wlo, h);
  k_att     <<<BB * NN / 4, 256, 0, stream>>>(h, att_src, att_dst, a_src, a_dst);
  k_out     <<<BB * (NN / 16), 256, 0, stream>>>(h, nbr, a_src, a_dst, bias, out);
}

// Round 12
// 397.495 us; speedup vs baseline: 2.0659x; 1.1186x over previous
//
#include <hip/hip_runtime.h>
#include <hip/hip_bf16.h>

#define BB 8
#define CC 128
#define NN 4096
#define HH 4
#define FF 128
#define KK 16
#define HF 512      // H*F
#define CAPH 128    // survivor capacity per query per half (stride 256 total)
#define WBUF 1536   // per-wave compaction buffer entries (20 sigma)

typedef __attribute__((ext_vector_type(8))) short short8v;
typedef __attribute__((ext_vector_type(8))) unsigned short ushort8v;
typedef __attribute__((ext_vector_type(4))) float f32x4;

__device__ __forceinline__ float bf2f(unsigned int u) {
  return __uint_as_float(u << 16);
}

__device__ __forceinline__ unsigned short f2bf(float f) {
  unsigned int u = __float_as_uint(f);
  unsigned int lsb = (u >> 16) & 1u;
  u += 0x7fffu + lsb;                 // RTNE
  return (unsigned short)(u >> 16);
}

__device__ __forceinline__ unsigned int umin2(unsigned int a, unsigned int b) {
  return a < b ? a : b;
}
__device__ __forceinline__ unsigned int umin3(unsigned int a, unsigned int b, unsigned int c) {
  return umin2(umin2(a, b), c);
}

// async global->LDS, 16B per lane; lds base must be wave-uniform
__device__ __forceinline__ void gload16(const void* gsrc, void* ldst) {
  __builtin_amdgcn_global_load_lds(
      (const __attribute__((address_space(1))) unsigned int*)gsrc,
      (__attribute__((address_space(3))) unsigned int*)ldst, 16, 0, 0);
}

// ---------------------------------------------------------------------------
// x[b][c][n] -> xt[b][n][c] (f32), xhi[b][n][c] (bf16), hsq[b][n] = 0.5*|x|^2
__launch_bounds__(256)
__global__ void k_split(const float* __restrict__ x,
                        float* __restrict__ xt,
                        unsigned short* __restrict__ xhi,
                        float* __restrict__ hsq) {
  __shared__ float Ls[CC][65];
  int b = blockIdx.x >> 6, nb = blockIdx.x & 63;
  int n0 = nb * 64;
  int tid = threadIdx.x;
  const float* xb = x + (size_t)b * CC * NN;

  for (int i = tid; i < CC * 64; i += 256) {
    int c = i >> 6, nl = i & 63;
    Ls[c][nl] = xb[(size_t)c * NN + n0 + nl];
  }
  __syncthreads();

  int n = tid >> 2, part = tid & 3;     // 64 n x 4 parts (32 c each)
  int node = b * NN + n0 + n;
  float sum = 0.f;
#pragma unroll
  for (int g = 0; g < 4; ++g) {
    float v[8];
    ushort8v ph;
#pragma unroll
    for (int j = 0; j < 8; ++j) {
      int c = part * 32 + g * 8 + j;
      v[j] = Ls[c][n];
      ph[j] = f2bf(v[j]);
      sum += v[j] * v[j];
    }
    float4 f0 = {v[0], v[1], v[2], v[3]};
    float4 f1 = {v[4], v[5], v[6], v[7]};
    *(float4*)&xt[(size_t)node * CC + part * 32 + g * 8] = f0;
    *(float4*)&xt[(size_t)node * CC + part * 32 + g * 8 + 4] = f1;
    *(ushort8v*)&xhi[(size_t)node * CC + part * 32 + g * 8] = ph;
  }
  sum += __shfl_xor(sum, 1, 64);
  sum += __shfl_xor(sum, 2, 64);
  if (part == 0) hsq[node] = 0.5f * sum;
}

// ---------------------------------------------------------------------------
// Pack W[c][hf] f32 -> Whi/Wlo[hf][c] bf16
__global__ void k_wpack(const float* __restrict__ W,
                        unsigned short* __restrict__ Whi,
                        unsigned short* __restrict__ Wlo) {
  int i = blockIdx.x * 256 + threadIdx.x;   // over 512*128
  int hf = i >> 7, c = i & 127;
  float v = W[(size_t)c * HF + hf];
  unsigned short hb = f2bf(v);
  Whi[i] = hb;
  Wlo[i] = f2bf(v - bf2f(hb));
}

// ---------------------------------------------------------------------------
// tau scan over candidates 0..1023 (subset): LDS-staged tiles (double-buffered
// global_load_lds, XOR-preswizzled source, XOR-swizzled read). Per-lane insert
// top-16, merge 4 lanes -> 16th-best key; thr[q] = floor16(key) - 0.5.
// XCD-pinned: batch = blockIdx & 7 (each XCD's L2 holds one batch's xhi slab).
__launch_bounds__(256)
__global__ void k_tauscan(const unsigned short* __restrict__ xhi,
                          const float* __restrict__ hsq,
                          float* __restrict__ thr) {
  __shared__ short8v AS[2][256];           // 8 KB staging (16 nodes x 16 granules)
  __shared__ unsigned int mv[4][16][64];   // 16 KB
  int b = blockIdx.x & 7, qg = blockIdx.x >> 3;   // XCD-pinned batch
  int w = threadIdx.x >> 6, lane = threadIdx.x & 63;
  int qcol = lane & 15, kg = lane >> 4;
  int base = b * NN;
  int q = base + qg * 64 + w * 16 + qcol;

  const short8v* XH = (const short8v*)xhi;   // granules: node*16 + ks*4 + kg
  short8v bh0 = XH[(size_t)q * 16 + kg];
  short8v bh1 = XH[(size_t)q * 16 + 4 + kg];
  short8v bh2 = XH[(size_t)q * 16 + 8 + kg];
  short8v bh3 = XH[(size_t)q * 16 + 12 + kg];

  // staging geometry: this wave fills nodes 4w..4w+3; LDS linear slot
  // (node, j) holds global granule (j ^ node) of node  [involution]
  int snode = w * 4 + (lane >> 4);
  int sgran = (lane & 15) ^ (snode & 15);

  gload16(xhi + ((size_t)(base + snode)) * 128 + sgran * 8, &AS[0][w * 64]);
  __syncthreads();

  unsigned int bd[16];
  unsigned int worst = 0;
  int cur = 0;

#pragma unroll 1
  for (int lt = 0; lt < 64; ++lt) {
    if (lt + 1 < 64)
      gload16(xhi + ((size_t)(base + (lt + 1) * 16 + snode)) * 128 + sgran * 8,
              &AS[cur ^ 1][w * 64]);
    short8v ah0 = AS[cur][qcol * 16 + ((0 + kg) ^ qcol)];
    short8v ah1 = AS[cur][qcol * 16 + ((4 + kg) ^ qcol)];
    short8v ah2 = AS[cur][qcol * 16 + ((8 + kg) ^ qcol)];
    short8v ah3 = AS[cur][qcol * 16 + ((12 + kg) ^ qcol)];
    f32x4 acc = {0.f, 0.f, 0.f, 0.f};
    acc = __builtin_amdgcn_mfma_f32_16x16x32_bf16(ah0, bh0, acc, 0, 0, 0);
    acc = __builtin_amdgcn_mfma_f32_16x16x32_bf16(ah1, bh1, acc, 0, 0, 0);
    acc = __builtin_amdgcn_mfma_f32_16x16x32_bf16(ah2, bh2, acc, 0, 0, 0);
    acc = __builtin_amdgcn_mfma_f32_16x16x32_bf16(ah3, bh3, acc, 0, 0, 0);
    float4 hs = *(const float4*)&hsq[base + lt * 16 + kg * 4];
    float hsa[4] = {hs.x, hs.y, hs.z, hs.w};

    if (lt < 4) {
#pragma unroll
      for (int r = 0; r < 4; ++r) {
        float tv = acc[r] - hsa[r] + 512.0f;
        bd[lt * 4 + r] = (__float_as_uint(tv) & ~1023u) | (1023u - (unsigned)(lt * 4 + r));
      }
      if (lt == 3) {
        unsigned int m0 = umin3(bd[0], bd[1], bd[2]);
        m0 = umin3(m0, bd[3], bd[4]);
        m0 = umin3(m0, bd[5], bd[6]);
        m0 = umin2(m0, bd[7]);
        unsigned int m1 = umin3(bd[8], bd[9], bd[10]);
        m1 = umin3(m1, bd[11], bd[12]);
        m1 = umin3(m1, bd[13], bd[14]);
        m1 = umin2(m1, bd[15]);
        worst = umin2(m0, m1);
      }
    } else {
#pragma unroll
      for (int r = 0; r < 4; ++r) {
        float tv = acc[r] - hsa[r] + 512.0f;
        unsigned int key = (__float_as_uint(tv) & ~1023u) | (1023u - (unsigned)(lt * 4 + r));
        if (key > worst) {
#pragma unroll
          for (int i = 0; i < 16; ++i) bd[i] = (bd[i] == worst) ? key : bd[i];
          unsigned int n0_ = umin3(bd[0], bd[1], bd[2]);
          n0_ = umin3(n0_, bd[3], bd[4]);
          n0_ = umin3(n0_, bd[5], bd[6]);
          n0_ = umin2(n0_, bd[7]);
          unsigned int n1_ = umin3(bd[8], bd[9], bd[10]);
          n1_ = umin3(n1_, bd[11], bd[12]);
          n1_ = umin3(n1_, bd[13], bd[14]);
          n1_ = umin2(n1_, bd[15]);
          worst = umin2(n0_, n1_);
        }
      }
    }
    __syncthreads();
    cur ^= 1;
  }

#pragma unroll
  for (int i = 0; i < 16; ++i) mv[w][qcol][kg * 16 + i] = bd[i];
  __syncthreads();

  if (lane < 16) {
    unsigned int tb[16];
#pragma unroll
    for (int i = 0; i < 16; ++i) tb[i] = mv[w][lane][i];
    unsigned int w0 = umin3(tb[0], tb[1], tb[2]);
    w0 = umin3(w0, tb[3], tb[4]);
    w0 = umin3(w0, tb[5], tb[6]);
    w0 = umin2(w0, tb[7]);
    unsigned int w1 = umin3(tb[8], tb[9], tb[10]);
    w1 = umin3(w1, tb[11], tb[12]);
    w1 = umin3(w1, tb[13], tb[14]);
    w1 = umin2(w1, tb[15]);
    unsigned int wst = umin2(w0, w1);
    for (int j = 16; j < 64; ++j) {
      unsigned int v = mv[w][lane][j];
      if (v > wst) {
        bool done = false;
#pragma unroll
        for (int i = 0; i < 16; ++i) {
          bool m = (!done) && (tb[i] == wst);
          done = done || m;
          tb[i] = m ? v : tb[i];
        }
        unsigned int a0 = umin3(tb[0], tb[1], tb[2]);
        a0 = umin3(a0, tb[3], tb[4]);
        a0 = umin3(a0, tb[5], tb[6]);
        a0 = umin2(a0, tb[7]);
        unsigned int a1 = umin3(tb[8], tb[9], tb[10]);
        a1 = umin3(a1, tb[11], tb[12]);
        a1 = umin3(a1, tb[13], tb[14]);
        a1 = umin2(a1, tb[15]);
        wst = umin2(a0, a1);
      }
    }
    thr[base + qg * 64 + w * 16 + lane] = __uint_as_float(wst & ~1023u) - 0.5f;
  }
}

// ---------------------------------------------------------------------------
// Collect survivors (tv >= thr[q]): LDS-staged tiles + ballot-compaction into
// per-wave LDS list, then bucket into per-(query,half) global lists.
// XCD-pinned: batch = blockIdx & 7.
__launch_bounds__(256)
__global__ void k_collect2(const unsigned short* __restrict__ xhi,
                           const float* __restrict__ hsq,
                           const float* __restrict__ thr,
                           unsigned short* __restrict__ cand,
                           unsigned short* __restrict__ qcnt) {
  __shared__ short8v AS[2][256];          // 8 KB staging
  __shared__ unsigned int buf[4][WBUF];   // 24 KB
  __shared__ unsigned int qc[4][16];
  int bx = blockIdx.x;
  int b = bx & 7, rest = bx >> 3;         // XCD-pinned batch; rest 0..127
  int qg = rest >> 1, ht = rest & 1;
  int w = threadIdx.x >> 6, lane = threadIdx.x & 63;
  int qcol = lane & 15, kg = lane >> 4;
  int base = b * NN;
  int q = base + qg * 64 + w * 16 + qcol;

  const short8v* XH = (const short8v*)xhi;
  short8v bh0 = XH[(size_t)q * 16 + kg];
  short8v bh1 = XH[(size_t)q * 16 + 4 + kg];
  short8v bh2 = XH[(size_t)q * 16 + 8 + kg];
  short8v bh3 = XH[(size_t)q * 16 + 12 + kg];
  float myThr = thr[q];
  if (lane < 16) qc[w][lane] = 0;

  int snode = w * 4 + (lane >> 4);
  int sgran = (lane & 15) ^ (snode & 15);

  gload16(xhi + ((size_t)(base + (ht * 128) * 16 + snode)) * 128 + sgran * 8,
          &AS[0][w * 64]);
  __syncthreads();

  int wbase = 0;
  unsigned long long ltmask = (1ull << lane) - 1ull;
  int cur = 0;

#pragma unroll 1
  for (int lt = 0; lt < 128; ++lt) {
    int t = ht * 128 + lt;
    if (lt + 1 < 128)
      gload16(xhi + ((size_t)(base + (t + 1) * 16 + snode)) * 128 + sgran * 8,
              &AS[cur ^ 1][w * 64]);
    short8v ah0 = AS[cur][qcol * 16 + ((0 + kg) ^ qcol)];
    short8v ah1 = AS[cur][qcol * 16 + ((4 + kg) ^ qcol)];
    short8v ah2 = AS[cur][qcol * 16 + ((8 + kg) ^ qcol)];
    short8v ah3 = AS[cur][qcol * 16 + ((12 + kg) ^ qcol)];
    f32x4 acc = {0.f, 0.f, 0.f, 0.f};
    acc = __builtin_amdgcn_mfma_f32_16x16x32_bf16(ah0, bh0, acc, 0, 0, 0);
    acc = __builtin_amdgcn_mfma_f32_16x16x32_bf16(ah1, bh1, acc, 0, 0, 0);
    acc = __builtin_amdgcn_mfma_f32_16x16x32_bf16(ah2, bh2, acc, 0, 0, 0);
    acc = __builtin_amdgcn_mfma_f32_16x16x32_bf16(ah3, bh3, acc, 0, 0, 0);
    float4 hs = *(const float4*)&hsq[base + t * 16 + kg * 4];
    float hsa[4] = {hs.x, hs.y, hs.z, hs.w};
#pragma unroll
    for (int r = 0; r < 4; ++r) {
      float tv = acc[r] - hsa[r] + 512.0f;
      bool pass = tv >= myThr;
      unsigned long long mask = __ballot(pass);
      if (mask) {
        int pos = wbase + (int)__popcll(mask & ltmask);
        if (pass && pos < WBUF)
          buf[w][pos] = ((unsigned)qcol << 12) | (unsigned)(t * 16 + kg * 4 + r);
        wbase += (int)__popcll(mask);
      }
    }
    __syncthreads();
    cur ^= 1;
  }
  if (wbase > WBUF) wbase = WBUF;

  for (int i = lane; i < wbase; i += 64) {
    unsigned int e = buf[w][i];
    int ql = (int)(e >> 12);
    unsigned int slot = atomicAdd(&qc[w][ql], 1u);
    if (slot < CAPH)
      cand[(size_t)(base + qg * 64 + w * 16 + ql) * (2 * CAPH) + ht * CAPH + slot] =
          (unsigned short)(e & 0xfffu);
  }
  __syncthreads();

  if (lane < 16) {
    unsigned int c = qc[w][lane];
    if (c > CAPH) c = CAPH;
    qcnt[(size_t)(base + qg * 64 + w * 16 + lane) * 2 + ht] = (unsigned short)c;
  }
}

// ---------------------------------------------------------------------------
// Exact f32 rerank, 8-lane cooperative, 8 candidates in flight per pass.
// XCD-pinned: batch = blockIdx & 7 -> each XCD's L2 holds its batch's 2MB xt.
__launch_bounds__(256)
__global__ void k_rerank(const float* __restrict__ xt, const float* __restrict__ hsq,
                         const unsigned short* __restrict__ cand,
                         const unsigned short* __restrict__ qcnt,
                         unsigned short* __restrict__ nbr) {
  __shared__ float pv[4][256];
  int w = threadIdx.x >> 6;
  int bid = blockIdx.x;
  int b = bid & 7, inner = bid >> 3;      // XCD-pinned batch; inner 0..1023
  int wq = (b << 12) + inner * 4 + w;
  int lane = threadIdx.x & 63;
  int base = b * NN;
  int n0 = qcnt[(size_t)wq * 2];
  int n1 = qcnt[(size_t)wq * 2 + 1];
  int nt = n0 + n1;                       // <= 256
  const float* qr = xt + (size_t)wq * CC;
  int cid = lane >> 3, part = lane & 7;

  // query chunks: phase ph covers floats ph*32 + part*4 .. +3
  float4 qv[4];
#pragma unroll
  for (int ph = 0; ph < 4; ++ph)
    qv[ph] = *(const float4*)&qr[ph * 32 + part * 4];

  int npass = (nt + 7) >> 3;
#pragma unroll 1
  for (int p = 0; p < npass; ++p) {
    int j = p * 8 + cid;
    bool valid = j < nt;
    int c = 0;
    if (valid)
      c = (j < n0) ? cand[(size_t)wq * (2 * CAPH) + j]
                   : cand[(size_t)wq * (2 * CAPH) + CAPH + (j - n0)];
    const float* cr = xt + (size_t)(base + c) * CC;
    float acc = 0.f;
#pragma unroll
    for (int ph = 0; ph < 4; ++ph) {
      float4 cv = *(const float4*)&cr[ph * 32 + part * 4];
      acc = fmaf(qv[ph].x, cv.x, acc);
      acc = fmaf(qv[ph].y, cv.y, acc);
      acc = fmaf(qv[ph].z, cv.z, acc);
      acc = fmaf(qv[ph].w, cv.w, acc);
    }
    acc += __shfl_xor(acc, 1, 64);
    acc += __shfl_xor(acc, 2, 64);
    acc += __shfl_xor(acc, 4, 64);
    if (part == 0)
      pv[w][p * 8 + cid] = valid ? (acc - hsq[base + c]) : -3.4e38f;
  }

  // selection over up to 256 values (4 slots per lane)
  float vs[4]; int is[4];
#pragma unroll
  for (int s = 0; s < 4; ++s) {
    int j = lane + s * 64;
    if (j < nt) {
      vs[s] = pv[w][j];
      is[s] = (j < n0) ? cand[(size_t)wq * (2 * CAPH) + j]
                       : cand[(size_t)wq * (2 * CAPH) + CAPH + (j - n0)];
    } else {
      vs[s] = -3.4e38f; is[s] = 0x7fffffff;
    }
  }

  unsigned short* o = nbr + (size_t)wq * KK;
  for (int s = 0; s < KK; ++s) {
    float bv = vs[0]; int bi_ = is[0];
#pragma unroll
    for (int t = 1; t < 4; ++t)
      if ((vs[t] > bv) || (vs[t] == bv && is[t] < bi_)) { bv = vs[t]; bi_ = is[t]; }
#pragma unroll
    for (int off = 1; off < 64; off <<= 1) {
      float ov = __shfl_xor(bv, off, 64);
      int oi = __shfl_xor(bi_, off, 64);
      bool take = (ov > bv) || (ov == bv && oi < bi_);
      bv = take ? ov : bv;
      bi_ = take ? oi : bi_;
    }
    if (lane == 0) o[s] = (unsigned short)bi_;
#pragma unroll
    for (int t = 0; t < 4; ++t)
      if (is[t] == bi_) { vs[t] = -3.4e38f; is[t] = 0x7fffffff; }
  }
}

// ---------------------------------------------------------------------------
// h = xt . W via 3-term split-bf16 MFMA (xhi*Whi + xhi*Wlo + xlo*Whi), bf16 out
__launch_bounds__(256)
__global__ void k_h2(const float* __restrict__ xt,
                     const unsigned short* __restrict__ Whi,
                     const unsigned short* __restrict__ Wlo,
                     unsigned short* __restrict__ hout) {
  int w = threadIdx.x >> 6, lane = threadIdx.x & 63;
  int r16 = lane & 15, kg = lane >> 4;
  int nd0 = blockIdx.x * 64 + w * 16;
  const float* arow = xt + (size_t)(nd0 + r16) * CC;
  short8v ahi[4], alo[4];
#pragma unroll
  for (int ks = 0; ks < 4; ++ks) {
    float4 f0 = *(const float4*)&arow[ks * 32 + kg * 8];
    float4 f1 = *(const float4*)&arow[ks * 32 + kg * 8 + 4];
    float fv[8] = {f0.x, f0.y, f0.z, f0.w, f1.x, f1.y, f1.z, f1.w};
    short8v hh_, ll_;
#pragma unroll
    for (int j = 0; j < 8; ++j) {
      unsigned short hb = f2bf(fv[j]);
      hh_[j] = (short)hb;
      ll_[j] = (short)f2bf(fv[j] - bf2f(hb));
    }
    ahi[ks] = hh_; alo[ks] = ll_;
  }
  const short8v* WH = (const short8v*)Whi;   // granule: hf*16 + ks*4 + kg
  const short8v* WL = (const short8v*)Wlo;
#pragma unroll 1
  for (int ct = 0; ct < 32; ++ct) {
    int hf = ct * 16 + r16;
    f32x4 acc = {0.f, 0.f, 0.f, 0.f};
#pragma unroll
    for (int ks = 0; ks < 4; ++ks) {
      short8v bh = WH[(size_t)hf * 16 + ks * 4 + kg];
      short8v bl = WL[(size_t)hf * 16 + ks * 4 + kg];
      acc = __builtin_amdgcn_mfma_f32_16x16x32_bf16(ahi[ks], bh, acc, 0, 0, 0);
      acc = __builtin_amdgcn_mfma_f32_16x16x32_bf16(ahi[ks], bl, acc, 0, 0, 0);
      acc = __builtin_amdgcn_mfma_f32_16x16x32_bf16(alo[ks], bh, acc, 0, 0, 0);
    }
#pragma unroll
    for (int r = 0; r < 4; ++r)
      hout[(size_t)(nd0 + kg * 4 + r) * HF + hf] = f2bf(acc[r]);
  }
}

// ---------------------------------------------------------------------------
// a_src/a_dst[b][n][h] = sum_f h[b][n][h][f] * att_{src,dst}[h][f]
__global__ void k_att(const unsigned short* __restrict__ h,
                      const float* __restrict__ att_src, const float* __restrict__ att_dst,
                      float* __restrict__ a_src, float* __restrict__ a_dst) {
  int gid = blockIdx.x * 256 + threadIdx.x;
  int wid = gid >> 6;            // node index b*N+n
  int lane = threadIdx.x & 63;
  uint4 v = ((const uint4*)(h + (size_t)wid * HF))[lane];
  float hv[8];
  hv[0] = bf2f(v.x & 0xffff); hv[1] = bf2f(v.x >> 16);
  hv[2] = bf2f(v.y & 0xffff); hv[3] = bf2f(v.y >> 16);
  hv[4] = bf2f(v.z & 0xffff); hv[5] = bf2f(v.z >> 16);
  hv[6] = bf2f(v.w & 0xffff); hv[7] = bf2f(v.w >> 16);
  int base = lane * 8;
  float s = 0.f, d = 0.f;
#pragma unroll
  for (int i = 0; i < 8; ++i) {
    s += hv[i] * att_src[base + i];
    d += hv[i] * att_dst[base + i];
  }
#pragma unroll
  for (int off = 1; off < 16; off <<= 1) {
    s += __shfl_xor(s, off, 64);
    d += __shfl_xor(d, off, 64);
  }
  if ((lane & 15) == 0) {
    int hh = lane >> 4;
    a_src[wid * HH + hh] = s;
    a_dst[wid * HH + hh] = d;
  }
}

// ---------------------------------------------------------------------------
// gather + softmax(k=16) + weighted sum + head-mean + bias + transpose store
// XCD-pinned: batch = blockIdx & 7 (h slab 4.2 MB/batch ~ L2-resident).
__launch_bounds__(256)
__global__ void k_out(const unsigned short* __restrict__ h,
                      const unsigned short* __restrict__ nbr,
                      const float* __restrict__ a_src, const float* __restrict__ a_dst,
                      const float* __restrict__ bias, float* __restrict__ out) {
  __shared__ float Ot[FF][17];
  int b = blockIdx.x & 7, nb = blockIdx.x >> 3;   // XCD-pinned batch; nb 0..255
  int w = threadIdx.x >> 6, lane = threadIdx.x & 63;
  int hh = lane >> 4, jj = lane & 15;

  for (int t = 0; t < 4; ++t) {
    int nl = w * 4 + t;
    int node = b * NN + nb * 16 + nl;
    int mj = nbr[node * KK + jj];

    float e = a_src[((size_t)b * NN + mj) * HH + hh] + a_dst[(size_t)node * HH + hh];
    e = e >= 0.f ? e : 0.2f * e;
    float m = e;
#pragma unroll
    for (int off = 1; off < 16; off <<= 1) m = fmaxf(m, __shfl_xor(m, off, 64));
    float p = expf(e - m);
    float sum = p;
#pragma unroll
    for (int off = 1; off < 16; off <<= 1) sum += __shfl_xor(sum, off, 64);
    float alpha = p / sum;

    float acc[8];
#pragma unroll
    for (int i = 0; i < 8; ++i) acc[i] = 0.f;

#pragma unroll
    for (int j = 0; j < 16; ++j) {
      float aj = __shfl(alpha, (hh << 4) | j, 64);
      int m2 = __shfl(mj, j, 64);
      uint4 v = ((const uint4*)(h + (size_t)(b * NN + m2) * HF))[lane];
      acc[0] += aj * bf2f(v.x & 0xffff); acc[1] += aj * bf2f(v.x >> 16);
      acc[2] += aj * bf2f(v.y & 0xffff); acc[3] += aj * bf2f(v.y >> 16);
      acc[4] += aj * bf2f(v.z & 0xffff); acc[5] += aj * bf2f(v.z >> 16);
      acc[6] += aj * bf2f(v.w & 0xffff); acc[7] += aj * bf2f(v.w >> 16);
    }

#pragma unroll
    for (int i = 0; i < 8; ++i) {
      acc[i] += __shfl_xor(acc[i], 16, 64);
      acc[i] += __shfl_xor(acc[i], 32, 64);
    }
    if (hh == 0) {
#pragma unroll
      for (int i = 0; i < 8; ++i) Ot[jj * 8 + i][nl] = acc[i] * 0.25f;
    }
  }
  __syncthreads();

#pragma unroll
  for (int it = 0; it < 8; ++it) {
    int idx = it * 256 + threadIdx.x;
    int f = idx >> 4, nl = idx & 15;
    out[((size_t)b * FF + f) * NN + nb * 16 + nl] = Ot[f][nl] + bias[f];
  }
}

// ---------------------------------------------------------------------------
extern "C" void kernel_launch(void* const* d_in, const int* in_sizes, int n_in,
                              void* d_out, int out_size, void* d_ws, size_t ws_size,
                              hipStream_t stream) {
  const float* x       = (const float*)d_in[0];
  const float* W       = (const float*)d_in[1];
  const float* att_src = (const float*)d_in[2];
  const float* att_dst = (const float*)d_in[3];
  const float* bias    = (const float*)d_in[4];

  char* ws = (char*)d_ws;
  // Lifetime-aliased layout; all sizes verified numerically (same as R8-R11):
  //   [0        ,16777216): xt    f32 32768*128*4 = 16,777,216 — split..rerank,h2
  //   [16777216 ,25165824): xhi   bf16 32768*128*2 = 8,388,608 — split..collect2
  //   [25165824 ,41943040): cand  u16 32768*256*2 = 16,777,216 — collect2..rerank
  //   [16777216 ,50331648): h     bf16 32768*512*2 = 33,554,432 — k_h2 AFTER rerank
  //   [50331648 ,51380224): nbr   u16 32768*16*2 = 1,048,576   — rerank..out
  //   [51380224 ,51511296): qcnt  u16 32768*2*2 = 131,072      — collect2..rerank
  //   [51511296 ,51642368): thr   f32 32768*4 = 131,072        — tauscan..collect2
  //   [51642368 ,51773440): hsq   f32 32768*4 = 131,072        — split..rerank
  //   [51773440 ,52297728): a_src f32 524,288 (aliased early by Whi+Wlo 2*131,072)
  //   [52297728 ,52822016): a_dst f32 524,288
  // total 52,822,016 B (proven envelope)
  float* xt            = (float*)ws;
  unsigned short* xhi  = (unsigned short*)(ws + 16777216);
  unsigned short* cand = (unsigned short*)(ws + 25165824);
  unsigned short* h    = (unsigned short*)(ws + 16777216);
  unsigned short* nbr  = (unsigned short*)(ws + 50331648);
  unsigned short* qcnt = (unsigned short*)(ws + 51380224);
  float* thr   = (float*)(ws + 51511296);
  float* hsq   = (float*)(ws + 51642368);
  float* a_src = (float*)(ws + 51773440);
  unsigned short* Whi  = (unsigned short*)(ws + 51773440);
  unsigned short* Wlo  = (unsigned short*)(ws + 51773440 + 131072);
  float* a_dst = (float*)(ws + 52297728);

  float* out = (float*)d_out;

  k_split   <<<BB * (NN / 64), 256, 0, stream>>>(x, xt, xhi, hsq);
  k_wpack   <<<HF * CC / 256, 256, 0, stream>>>(W, Whi, Wlo);
  k_tauscan <<<BB * 64, 256, 0, stream>>>(xhi, hsq, thr);
  k_collect2<<<BB * 64 * 2, 256, 0, stream>>>(xhi, hsq, thr, cand, qcnt);
  k_rerank  <<<BB * NN / 4, 256, 0, stream>>>(xt, hsq, cand, qcnt, nbr);
  k_h2      <<<BB * NN / 64, 256, 0, stream>>>(xt, Whi, Wlo, h);
  k_att     <<<BB * NN / 4, 256, 0, stream>>>(h, att_src, att_dst, a_src, a_dst);
  k_out     <<<BB * (NN / 16), 256, 0, stream>>>(h, nbr, a_src, a_dst, bias, out);
}

// Round 13
// 377.601 us; speedup vs baseline: 2.1747x; 1.0527x over previous
//
#include <hip/hip_runtime.h>
#include <hip/hip_bf16.h>

#define BB 8
#define CC 128
#define NN 4096
#define HH 4
#define FF 128
#define KK 16
#define HF 512      // H*F
#define CAPH 128    // survivor capacity per query per half (stride 256 total)
#define WBUF 1536   // per-wave compaction buffer entries (20 sigma)

typedef __attribute__((ext_vector_type(8))) short short8v;
typedef __attribute__((ext_vector_type(8))) unsigned short ushort8v;
typedef __attribute__((ext_vector_type(4))) float f32x4;

__device__ __forceinline__ float bf2f(unsigned int u) {
  return __uint_as_float(u << 16);
}

__device__ __forceinline__ unsigned short f2bf(float f) {
  unsigned int u = __float_as_uint(f);
  unsigned int lsb = (u >> 16) & 1u;
  u += 0x7fffu + lsb;                 // RTNE
  return (unsigned short)(u >> 16);
}

__device__ __forceinline__ unsigned int umin2(unsigned int a, unsigned int b) {
  return a < b ? a : b;
}
__device__ __forceinline__ unsigned int umin3(unsigned int a, unsigned int b, unsigned int c) {
  return umin2(umin2(a, b), c);
}

// async global->LDS, 16B per lane; lds base must be wave-uniform
__device__ __forceinline__ void gload16(const void* gsrc, void* ldst) {
  __builtin_amdgcn_global_load_lds(
      (const __attribute__((address_space(1))) unsigned int*)gsrc,
      (__attribute__((address_space(3))) unsigned int*)ldst, 16, 0, 0);
}

// ---------------------------------------------------------------------------
// x[b][c][n] -> xt[b][n][c] (f32), xhi[b][n][c] (bf16), hsq[b][n] = 0.5*|x|^2
__launch_bounds__(256)
__global__ void k_split(const float* __restrict__ x,
                        float* __restrict__ xt,
                        unsigned short* __restrict__ xhi,
                        float* __restrict__ hsq) {
  __shared__ float Ls[CC][65];
  int b = blockIdx.x >> 6, nb = blockIdx.x & 63;
  int n0 = nb * 64;
  int tid = threadIdx.x;
  const float* xb = x + (size_t)b * CC * NN;

  for (int i = tid; i < CC * 64; i += 256) {
    int c = i >> 6, nl = i & 63;
    Ls[c][nl] = xb[(size_t)c * NN + n0 + nl];
  }
  __syncthreads();

  int n = tid >> 2, part = tid & 3;     // 64 n x 4 parts (32 c each)
  int node = b * NN + n0 + n;
  float sum = 0.f;
#pragma unroll
  for (int g = 0; g < 4; ++g) {
    float v[8];
    ushort8v ph;
#pragma unroll
    for (int j = 0; j < 8; ++j) {
      int c = part * 32 + g * 8 + j;
      v[j] = Ls[c][n];
      ph[j] = f2bf(v[j]);
      sum += v[j] * v[j];
    }
    float4 f0 = {v[0], v[1], v[2], v[3]};
    float4 f1 = {v[4], v[5], v[6], v[7]};
    *(float4*)&xt[(size_t)node * CC + part * 32 + g * 8] = f0;
    *(float4*)&xt[(size_t)node * CC + part * 32 + g * 8 + 4] = f1;
    *(ushort8v*)&xhi[(size_t)node * CC + part * 32 + g * 8] = ph;
  }
  sum += __shfl_xor(sum, 1, 64);
  sum += __shfl_xor(sum, 2, 64);
  if (part == 0) hsq[node] = 0.5f * sum;
}

// ---------------------------------------------------------------------------
// Pack W[c][hf] f32 -> Whi/Wlo[hf][c] bf16
__global__ void k_wpack(const float* __restrict__ W,
                        unsigned short* __restrict__ Whi,
                        unsigned short* __restrict__ Wlo) {
  int i = blockIdx.x * 256 + threadIdx.x;   // over 512*128
  int hf = i >> 7, c = i & 127;
  float v = W[(size_t)c * HF + hf];
  unsigned short hb = f2bf(v);
  Whi[i] = hb;
  Wlo[i] = f2bf(v - bf2f(hb));
}

// ---------------------------------------------------------------------------
// tau scan over candidates 0..1023 (subset): LDS-staged tiles (double-buffered
// global_load_lds, XOR-preswizzled source, XOR-swizzled read). Per-lane insert
// top-16, merge 4 lanes -> 16th-best key; thr[q] = floor16(key) - 0.5.
// XCD-pinned: batch = blockIdx & 7 (each XCD's L2 holds one batch's xhi slab).
__launch_bounds__(256)
__global__ void k_tauscan(const unsigned short* __restrict__ xhi,
                          const float* __restrict__ hsq,
                          float* __restrict__ thr) {
  __shared__ short8v AS[2][256];           // 8 KB staging (16 nodes x 16 granules)
  __shared__ unsigned int mv[4][16][64];   // 16 KB
  int b = blockIdx.x & 7, qg = blockIdx.x >> 3;   // XCD-pinned batch
  int w = threadIdx.x >> 6, lane = threadIdx.x & 63;
  int qcol = lane & 15, kg = lane >> 4;
  int base = b * NN;
  int q = base + qg * 64 + w * 16 + qcol;

  const short8v* XH = (const short8v*)xhi;   // granules: node*16 + ks*4 + kg
  short8v bh0 = XH[(size_t)q * 16 + kg];
  short8v bh1 = XH[(size_t)q * 16 + 4 + kg];
  short8v bh2 = XH[(size_t)q * 16 + 8 + kg];
  short8v bh3 = XH[(size_t)q * 16 + 12 + kg];

  // staging geometry: this wave fills nodes 4w..4w+3; LDS linear slot
  // (node, j) holds global granule (j ^ node) of node  [involution]
  int snode = w * 4 + (lane >> 4);
  int sgran = (lane & 15) ^ (snode & 15);

  gload16(xhi + ((size_t)(base + snode)) * 128 + sgran * 8, &AS[0][w * 64]);
  __syncthreads();

  unsigned int bd[16];
  unsigned int worst = 0;
  int cur = 0;

#pragma unroll 1
  for (int lt = 0; lt < 64; ++lt) {
    if (lt + 1 < 64)
      gload16(xhi + ((size_t)(base + (lt + 1) * 16 + snode)) * 128 + sgran * 8,
              &AS[cur ^ 1][w * 64]);
    short8v ah0 = AS[cur][qcol * 16 + ((0 + kg) ^ qcol)];
    short8v ah1 = AS[cur][qcol * 16 + ((4 + kg) ^ qcol)];
    short8v ah2 = AS[cur][qcol * 16 + ((8 + kg) ^ qcol)];
    short8v ah3 = AS[cur][qcol * 16 + ((12 + kg) ^ qcol)];
    f32x4 acc = {0.f, 0.f, 0.f, 0.f};
    acc = __builtin_amdgcn_mfma_f32_16x16x32_bf16(ah0, bh0, acc, 0, 0, 0);
    acc = __builtin_amdgcn_mfma_f32_16x16x32_bf16(ah1, bh1, acc, 0, 0, 0);
    acc = __builtin_amdgcn_mfma_f32_16x16x32_bf16(ah2, bh2, acc, 0, 0, 0);
    acc = __builtin_amdgcn_mfma_f32_16x16x32_bf16(ah3, bh3, acc, 0, 0, 0);
    float4 hs = *(const float4*)&hsq[base + lt * 16 + kg * 4];
    float hsa[4] = {hs.x, hs.y, hs.z, hs.w};

    if (lt < 4) {
#pragma unroll
      for (int r = 0; r < 4; ++r) {
        float tv = acc[r] - hsa[r] + 512.0f;
        bd[lt * 4 + r] = (__float_as_uint(tv) & ~1023u) | (1023u - (unsigned)(lt * 4 + r));
      }
      if (lt == 3) {
        unsigned int m0 = umin3(bd[0], bd[1], bd[2]);
        m0 = umin3(m0, bd[3], bd[4]);
        m0 = umin3(m0, bd[5], bd[6]);
        m0 = umin2(m0, bd[7]);
        unsigned int m1 = umin3(bd[8], bd[9], bd[10]);
        m1 = umin3(m1, bd[11], bd[12]);
        m1 = umin3(m1, bd[13], bd[14]);
        m1 = umin2(m1, bd[15]);
        worst = umin2(m0, m1);
      }
    } else {
#pragma unroll
      for (int r = 0; r < 4; ++r) {
        float tv = acc[r] - hsa[r] + 512.0f;
        unsigned int key = (__float_as_uint(tv) & ~1023u) | (1023u - (unsigned)(lt * 4 + r));
        if (key > worst) {
#pragma unroll
          for (int i = 0; i < 16; ++i) bd[i] = (bd[i] == worst) ? key : bd[i];
          unsigned int n0_ = umin3(bd[0], bd[1], bd[2]);
          n0_ = umin3(n0_, bd[3], bd[4]);
          n0_ = umin3(n0_, bd[5], bd[6]);
          n0_ = umin2(n0_, bd[7]);
          unsigned int n1_ = umin3(bd[8], bd[9], bd[10]);
          n1_ = umin3(n1_, bd[11], bd[12]);
          n1_ = umin3(n1_, bd[13], bd[14]);
          n1_ = umin2(n1_, bd[15]);
          worst = umin2(n0_, n1_);
        }
      }
    }
    __syncthreads();
    cur ^= 1;
  }

#pragma unroll
  for (int i = 0; i < 16; ++i) mv[w][qcol][kg * 16 + i] = bd[i];
  __syncthreads();

  if (lane < 16) {
    unsigned int tb[16];
#pragma unroll
    for (int i = 0; i < 16; ++i) tb[i] = mv[w][lane][i];
    unsigned int w0 = umin3(tb[0], tb[1], tb[2]);
    w0 = umin3(w0, tb[3], tb[4]);
    w0 = umin3(w0, tb[5], tb[6]);
    w0 = umin2(w0, tb[7]);
    unsigned int w1 = umin3(tb[8], tb[9], tb[10]);
    w1 = umin3(w1, tb[11], tb[12]);
    w1 = umin3(w1, tb[13], tb[14]);
    w1 = umin2(w1, tb[15]);
    unsigned int wst = umin2(w0, w1);
    for (int j = 16; j < 64; ++j) {
      unsigned int v = mv[w][lane][j];
      if (v > wst) {
        bool done = false;
#pragma unroll
        for (int i = 0; i < 16; ++i) {
          bool m = (!done) && (tb[i] == wst);
          done = done || m;
          tb[i] = m ? v : tb[i];
        }
        unsigned int a0 = umin3(tb[0], tb[1], tb[2]);
        a0 = umin3(a0, tb[3], tb[4]);
        a0 = umin3(a0, tb[5], tb[6]);
        a0 = umin2(a0, tb[7]);
        unsigned int a1 = umin3(tb[8], tb[9], tb[10]);
        a1 = umin3(a1, tb[11], tb[12]);
        a1 = umin3(a1, tb[13], tb[14]);
        a1 = umin2(a1, tb[15]);
        wst = umin2(a0, a1);
      }
    }
    thr[base + qg * 64 + w * 16 + lane] = __uint_as_float(wst & ~1023u) - 0.5f;
  }
}

// ---------------------------------------------------------------------------
// Collect survivors (tv >= thr[q]): LDS-staged tiles + ballot-compaction into
// per-wave LDS list, then bucket into per-(query,half) global lists.
// XCD-pinned: batch = blockIdx & 7.
__launch_bounds__(256)
__global__ void k_collect2(const unsigned short* __restrict__ xhi,
                           const float* __restrict__ hsq,
                           const float* __restrict__ thr,
                           unsigned short* __restrict__ cand,
                           unsigned short* __restrict__ qcnt) {
  __shared__ short8v AS[2][256];          // 8 KB staging
  __shared__ unsigned int buf[4][WBUF];   // 24 KB
  __shared__ unsigned int qc[4][16];
  int bx = blockIdx.x;
  int b = bx & 7, rest = bx >> 3;         // XCD-pinned batch; rest 0..127
  int qg = rest >> 1, ht = rest & 1;
  int w = threadIdx.x >> 6, lane = threadIdx.x & 63;
  int qcol = lane & 15, kg = lane >> 4;
  int base = b * NN;
  int q = base + qg * 64 + w * 16 + qcol;

  const short8v* XH = (const short8v*)xhi;
  short8v bh0 = XH[(size_t)q * 16 + kg];
  short8v bh1 = XH[(size_t)q * 16 + 4 + kg];
  short8v bh2 = XH[(size_t)q * 16 + 8 + kg];
  short8v bh3 = XH[(size_t)q * 16 + 12 + kg];
  float myThr = thr[q];
  if (lane < 16) qc[w][lane] = 0;

  int snode = w * 4 + (lane >> 4);
  int sgran = (lane & 15) ^ (snode & 15);

  gload16(xhi + ((size_t)(base + (ht * 128) * 16 + snode)) * 128 + sgran * 8,
          &AS[0][w * 64]);
  __syncthreads();

  int wbase = 0;
  unsigned long long ltmask = (1ull << lane) - 1ull;
  int cur = 0;

#pragma unroll 1
  for (int lt = 0; lt < 128; ++lt) {
    int t = ht * 128 + lt;
    if (lt + 1 < 128)
      gload16(xhi + ((size_t)(base + (t + 1) * 16 + snode)) * 128 + sgran * 8,
              &AS[cur ^ 1][w * 64]);
    short8v ah0 = AS[cur][qcol * 16 + ((0 + kg) ^ qcol)];
    short8v ah1 = AS[cur][qcol * 16 + ((4 + kg) ^ qcol)];
    short8v ah2 = AS[cur][qcol * 16 + ((8 + kg) ^ qcol)];
    short8v ah3 = AS[cur][qcol * 16 + ((12 + kg) ^ qcol)];
    f32x4 acc = {0.f, 0.f, 0.f, 0.f};
    acc = __builtin_amdgcn_mfma_f32_16x16x32_bf16(ah0, bh0, acc, 0, 0, 0);
    acc = __builtin_amdgcn_mfma_f32_16x16x32_bf16(ah1, bh1, acc, 0, 0, 0);
    acc = __builtin_amdgcn_mfma_f32_16x16x32_bf16(ah2, bh2, acc, 0, 0, 0);
    acc = __builtin_amdgcn_mfma_f32_16x16x32_bf16(ah3, bh3, acc, 0, 0, 0);
    float4 hs = *(const float4*)&hsq[base + t * 16 + kg * 4];
    float hsa[4] = {hs.x, hs.y, hs.z, hs.w};
#pragma unroll
    for (int r = 0; r < 4; ++r) {
      float tv = acc[r] - hsa[r] + 512.0f;
      bool pass = tv >= myThr;
      unsigned long long mask = __ballot(pass);
      if (mask) {
        int pos = wbase + (int)__popcll(mask & ltmask);
        if (pass && pos < WBUF)
          buf[w][pos] = ((unsigned)qcol << 12) | (unsigned)(t * 16 + kg * 4 + r);
        wbase += (int)__popcll(mask);
      }
    }
    __syncthreads();
    cur ^= 1;
  }
  if (wbase > WBUF) wbase = WBUF;

  for (int i = lane; i < wbase; i += 64) {
    unsigned int e = buf[w][i];
    int ql = (int)(e >> 12);
    unsigned int slot = atomicAdd(&qc[w][ql], 1u);
    if (slot < CAPH)
      cand[(size_t)(base + qg * 64 + w * 16 + ql) * (2 * CAPH) + ht * CAPH + slot] =
          (unsigned short)(e & 0xfffu);
  }
  __syncthreads();

  if (lane < 16) {
    unsigned int c = qc[w][lane];
    if (c > CAPH) c = CAPH;
    qcnt[(size_t)(base + qg * 64 + w * 16 + lane) * 2 + ht] = (unsigned short)c;
  }
}

// ---------------------------------------------------------------------------
// Exact f32 rerank, 8-lane cooperative dot phase; selection via per-lane
// sorted-4 lists + val-only butterfly argmax + ballot/ffs winner broadcast
// (96 bpermutes vs 192 for the (val,idx)-pair butterfly). Exact-tie path
// (wave-uniform, ~never taken) does an idx-min reduce -> identical semantics.
__launch_bounds__(256)
__global__ void k_rerank(const float* __restrict__ xt, const float* __restrict__ hsq,
                         const unsigned short* __restrict__ cand,
                         const unsigned short* __restrict__ qcnt,
                         unsigned short* __restrict__ nbr) {
  __shared__ float pv[4][256];
  int w = threadIdx.x >> 6;
  int bid = blockIdx.x;
  int b = bid & 7, inner = bid >> 3;      // XCD-pinned batch; inner 0..1023
  int wq = (b << 12) + inner * 4 + w;
  int lane = threadIdx.x & 63;
  int base = b * NN;
  int n0 = qcnt[(size_t)wq * 2];
  int n1 = qcnt[(size_t)wq * 2 + 1];
  int nt = n0 + n1;                       // <= 256
  const float* qr = xt + (size_t)wq * CC;
  int cid = lane >> 3, part = lane & 7;

  // query chunks: phase ph covers floats ph*32 + part*4 .. +3
  float4 qv[4];
#pragma unroll
  for (int ph = 0; ph < 4; ++ph)
    qv[ph] = *(const float4*)&qr[ph * 32 + part * 4];

  int npass = (nt + 7) >> 3;
#pragma unroll 2
  for (int p = 0; p < npass; ++p) {
    int j = p * 8 + cid;
    bool valid = j < nt;
    int c = 0;
    if (valid)
      c = (j < n0) ? cand[(size_t)wq * (2 * CAPH) + j]
                   : cand[(size_t)wq * (2 * CAPH) + CAPH + (j - n0)];
    const float* cr = xt + (size_t)(base + c) * CC;
    float acc = 0.f;
#pragma unroll
    for (int ph = 0; ph < 4; ++ph) {
      float4 cv = *(const float4*)&cr[ph * 32 + part * 4];
      acc = fmaf(qv[ph].x, cv.x, acc);
      acc = fmaf(qv[ph].y, cv.y, acc);
      acc = fmaf(qv[ph].z, cv.z, acc);
      acc = fmaf(qv[ph].w, cv.w, acc);
    }
    acc += __shfl_xor(acc, 1, 64);
    acc += __shfl_xor(acc, 2, 64);
    acc += __shfl_xor(acc, 4, 64);
    if (part == 0)
      pv[w][p * 8 + cid] = valid ? (acc - hsq[base + c]) : -3.4e38f;
  }

  // load 4 slots per lane, sort locally by (val desc, idx asc)
  float v0, v1, v2, v3;
  int i0, i1, i2, i3;
  {
    float tv[4]; int ti[4];
#pragma unroll
    for (int s = 0; s < 4; ++s) {
      int j = lane + s * 64;
      if (j < nt) {
        tv[s] = pv[w][j];
        ti[s] = (j < n0) ? cand[(size_t)wq * (2 * CAPH) + j]
                         : cand[(size_t)wq * (2 * CAPH) + CAPH + (j - n0)];
      } else {
        tv[s] = -3.4e38f; ti[s] = 0x7fffffff;
      }
    }
    v0 = tv[0]; v1 = tv[1]; v2 = tv[2]; v3 = tv[3];
    i0 = ti[0]; i1 = ti[1]; i2 = ti[2]; i3 = ti[3];
  }
#define CE(va, ia, vb, ib)                                        \
  {                                                               \
    bool sw_ = (vb > va) || (vb == va && ib < ia);                \
    float tv_ = va; int ti_ = ia;                                 \
    va = sw_ ? vb : va; ia = sw_ ? ib : ia;                       \
    vb = sw_ ? tv_ : vb; ib = sw_ ? ti_ : ib;                     \
  }
  CE(v0, i0, v1, i1); CE(v2, i2, v3, i3);
  CE(v0, i0, v2, i2); CE(v1, i1, v3, i3);
  CE(v1, i1, v2, i2);
#undef CE

  unsigned short* o = nbr + (size_t)wq * KK;
  for (int s = 0; s < KK; ++s) {
    float bv = v0;
#pragma unroll
    for (int off = 1; off < 64; off <<= 1)
      bv = fmaxf(bv, __shfl_xor(bv, off, 64));
    unsigned long long own = __ballot(v0 == bv);
    int wi;
    bool owner;
    if (__popcll(own) > 1) {           // exact-tie path (wave-uniform, rare)
      int ci = (v0 == bv) ? i0 : 0x7fffffff;
#pragma unroll
      for (int off = 1; off < 64; off <<= 1) {
        int oc = __shfl_xor(ci, off, 64);
        ci = oc < ci ? oc : ci;
      }
      wi = ci;
      owner = (v0 == bv) && (i0 == ci);
    } else {
      int first = (int)__ffsll((unsigned long long)own) - 1;
      wi = __shfl(i0, first, 64);
      owner = (lane == first);
    }
    if (lane == 0) o[s] = (unsigned short)wi;
    if (owner) {
      v0 = v1; i0 = i1;
      v1 = v2; i1 = i2;
      v2 = v3; i2 = i3;
      v3 = -3.4e38f; i3 = 0x7fffffff;
    }
  }
}

// ---------------------------------------------------------------------------
// h = xt . W via 3-term split-bf16 MFMA (xhi*Whi + xhi*Wlo + xlo*Whi), bf16 out
__launch_bounds__(256)
__global__ void k_h2(const float* __restrict__ xt,
                     const unsigned short* __restrict__ Whi,
                     const unsigned short* __restrict__ Wlo,
                     unsigned short* __restrict__ hout) {
  int w = threadIdx.x >> 6, lane = threadIdx.x & 63;
  int r16 = lane & 15, kg = lane >> 4;
  int nd0 = blockIdx.x * 64 + w * 16;
  const float* arow = xt + (size_t)(nd0 + r16) * CC;
  short8v ahi[4], alo[4];
#pragma unroll
  for (int ks = 0; ks < 4; ++ks) {
    float4 f0 = *(const float4*)&arow[ks * 32 + kg * 8];
    float4 f1 = *(const float4*)&arow[ks * 32 + kg * 8 + 4];
    float fv[8] = {f0.x, f0.y, f0.z, f0.w, f1.x, f1.y, f1.z, f1.w};
    short8v hh_, ll_;
#pragma unroll
    for (int j = 0; j < 8; ++j) {
      unsigned short hb = f2bf(fv[j]);
      hh_[j] = (short)hb;
      ll_[j] = (short)f2bf(fv[j] - bf2f(hb));
    }
    ahi[ks] = hh_; alo[ks] = ll_;
  }
  const short8v* WH = (const short8v*)Whi;   // granule: hf*16 + ks*4 + kg
  const short8v* WL = (const short8v*)Wlo;
#pragma unroll 1
  for (int ct = 0; ct < 32; ++ct) {
    int hf = ct * 16 + r16;
    f32x4 acc = {0.f, 0.f, 0.f, 0.f};
#pragma unroll
    for (int ks = 0; ks < 4; ++ks) {
      short8v bh = WH[(size_t)hf * 16 + ks * 4 + kg];
      short8v bl = WL[(size_t)hf * 16 + ks * 4 + kg];
      acc = __builtin_amdgcn_mfma_f32_16x16x32_bf16(ahi[ks], bh, acc, 0, 0, 0);
      acc = __builtin_amdgcn_mfma_f32_16x16x32_bf16(ahi[ks], bl, acc, 0, 0, 0);
      acc = __builtin_amdgcn_mfma_f32_16x16x32_bf16(alo[ks], bh, acc, 0, 0, 0);
    }
#pragma unroll
    for (int r = 0; r < 4; ++r)
      hout[(size_t)(nd0 + kg * 4 + r) * HF + hf] = f2bf(acc[r]);
  }
}

// ---------------------------------------------------------------------------
// a_src/a_dst[b][n][h] = sum_f h[b][n][h][f] * att_{src,dst}[h][f]
__global__ void k_att(const unsigned short* __restrict__ h,
                      const float* __restrict__ att_src, const float* __restrict__ att_dst,
                      float* __restrict__ a_src, float* __restrict__ a_dst) {
  int gid = blockIdx.x * 256 + threadIdx.x;
  int wid = gid >> 6;            // node index b*N+n
  int lane = threadIdx.x & 63;
  uint4 v = ((const uint4*)(h + (size_t)wid * HF))[lane];
  float hv[8];
  hv[0] = bf2f(v.x & 0xffff); hv[1] = bf2f(v.x >> 16);
  hv[2] = bf2f(v.y & 0xffff); hv[3] = bf2f(v.y >> 16);
  hv[4] = bf2f(v.z & 0xffff); hv[5] = bf2f(v.z >> 16);
  hv[6] = bf2f(v.w & 0xffff); hv[7] = bf2f(v.w >> 16);
  int base = lane * 8;
  float s = 0.f, d = 0.f;
#pragma unroll
  for (int i = 0; i < 8; ++i) {
    s += hv[i] * att_src[base + i];
    d += hv[i] * att_dst[base + i];
  }
#pragma unroll
  for (int off = 1; off < 16; off <<= 1) {
    s += __shfl_xor(s, off, 64);
    d += __shfl_xor(d, off, 64);
  }
  if ((lane & 15) == 0) {
    int hh = lane >> 4;
    a_src[wid * HH + hh] = s;
    a_dst[wid * HH + hh] = d;
  }
}

// ---------------------------------------------------------------------------
// gather + softmax(k=16) + weighted sum + head-mean + bias + transpose store
// XCD-pinned: batch = blockIdx & 7 (h slab 4.2 MB/batch ~ L2-resident).
__launch_bounds__(256)
__global__ void k_out(const unsigned short* __restrict__ h,
                      const unsigned short* __restrict__ nbr,
                      const float* __restrict__ a_src, const float* __restrict__ a_dst,
                      const float* __restrict__ bias, float* __restrict__ out) {
  __shared__ float Ot[FF][17];
  int b = blockIdx.x & 7, nb = blockIdx.x >> 3;   // XCD-pinned batch; nb 0..255
  int w = threadIdx.x >> 6, lane = threadIdx.x & 63;
  int hh = lane >> 4, jj = lane & 15;

  for (int t = 0; t < 4; ++t) {
    int nl = w * 4 + t;
    int node = b * NN + nb * 16 + nl;
    int mj = nbr[node * KK + jj];

    float e = a_src[((size_t)b * NN + mj) * HH + hh] + a_dst[(size_t)node * HH + hh];
    e = e >= 0.f ? e : 0.2f * e;
    float m = e;
#pragma unroll
    for (int off = 1; off < 16; off <<= 1) m = fmaxf(m, __shfl_xor(m, off, 64));
    float p = expf(e - m);
    float sum = p;
#pragma unroll
    for (int off = 1; off < 16; off <<= 1) sum += __shfl_xor(sum, off, 64);
    float alpha = p / sum;

    float acc[8];
#pragma unroll
    for (int i = 0; i < 8; ++i) acc[i] = 0.f;

#pragma unroll
    for (int j = 0; j < 16; ++j) {
      float aj = __shfl(alpha, (hh << 4) | j, 64);
      int m2 = __shfl(mj, j, 64);
      uint4 v = ((const uint4*)(h + (size_t)(b * NN + m2) * HF))[lane];
      acc[0] += aj * bf2f(v.x & 0xffff); acc[1] += aj * bf2f(v.x >> 16);
      acc[2] += aj * bf2f(v.y & 0xffff); acc[3] += aj * bf2f(v.y >> 16);
      acc[4] += aj * bf2f(v.z & 0xffff); acc[5] += aj * bf2f(v.z >> 16);
      acc[6] += aj * bf2f(v.w & 0xffff); acc[7] += aj * bf2f(v.w >> 16);
    }

#pragma unroll
    for (int i = 0; i < 8; ++i) {
      acc[i] += __shfl_xor(acc[i], 16, 64);
      acc[i] += __shfl_xor(acc[i], 32, 64);
    }
    if (hh == 0) {
#pragma unroll
      for (int i = 0; i < 8; ++i) Ot[jj * 8 + i][nl] = acc[i] * 0.25f;
    }
  }
  __syncthreads();

#pragma unroll
  for (int it = 0; it < 8; ++it) {
    int idx = it * 256 + threadIdx.x;
    int f = idx >> 4, nl = idx & 15;
    out[((size_t)b * FF + f) * NN + nb * 16 + nl] = Ot[f][nl] + bias[f];
  }
}

// ---------------------------------------------------------------------------
extern "C" void kernel_launch(void* const* d_in, const int* in_sizes, int n_in,
                              void* d_out, int out_size, void* d_ws, size_t ws_size,
                              hipStream_t stream) {
  const float* x       = (const float*)d_in[0];
  const float* W       = (const float*)d_in[1];
  const float* att_src = (const float*)d_in[2];
  const float* att_dst = (const float*)d_in[3];
  const float* bias    = (const float*)d_in[4];

  char* ws = (char*)d_ws;
  // Lifetime-aliased layout; all sizes verified numerically (same as R8-R12):
  //   [0        ,16777216): xt    f32 32768*128*4 = 16,777,216 — split..rerank,h2
  //   [16777216 ,25165824): xhi   bf16 32768*128*2 = 8,388,608 — split..collect2
  //   [25165824 ,41943040): cand  u16 32768*256*2 = 16,777,216 — collect2..rerank
  //   [16777216 ,50331648): h     bf16 32768*512*2 = 33,554,432 — k_h2 AFTER rerank
  //   [50331648 ,51380224): nbr   u16 32768*16*2 = 1,048,576   — rerank..out
  //   [51380224 ,51511296): qcnt  u16 32768*2*2 = 131,072      — collect2..rerank
  //   [51511296 ,51642368): thr   f32 32768*4 = 131,072        — tauscan..collect2
  //   [51642368 ,51773440): hsq   f32 32768*4 = 131,072        — split..rerank
  //   [51773440 ,52297728): a_src f32 524,288 (aliased early by Whi+Wlo 2*131,072)
  //   [52297728 ,52822016): a_dst f32 524,288
  // total 52,822,016 B (proven envelope)
  float* xt            = (float*)ws;
  unsigned short* xhi  = (unsigned short*)(ws + 16777216);
  unsigned short* cand = (unsigned short*)(ws + 25165824);
  unsigned short* h    = (unsigned short*)(ws + 16777216);
  unsigned short* nbr  = (unsigned short*)(ws + 50331648);
  unsigned short* qcnt = (unsigned short*)(ws + 51380224);
  float* thr   = (float*)(ws + 51511296);
  float* hsq   = (float*)(ws + 51642368);
  float* a_src = (float*)(ws + 51773440);
  unsigned short* Whi  = (unsigned short*)(ws + 51773440);
  unsigned short* Wlo  = (unsigned short*)(ws + 51773440 + 131072);
  float* a_dst = (float*)(ws + 52297728);

  float* out = (float*)d_out;

  k_split   <<<BB * (NN / 64), 256, 0, stream>>>(x, xt, xhi, hsq);
  k_wpack   <<<HF * CC / 256, 256, 0, stream>>>(W, Whi, Wlo);
  k_tauscan <<<BB * 64, 256, 0, stream>>>(xhi, hsq, thr);
  k_collect2<<<BB * 64 * 2, 256, 0, stream>>>(xhi, hsq, thr, cand, qcnt);
  k_rerank  <<<BB * NN / 4, 256, 0, stream>>>(xt, hsq, cand, qcnt, nbr);
  k_h2      <<<BB * NN / 64, 256, 0, stream>>>(xt, Whi, Wlo, h);
  k_att     <<<BB * NN / 4, 256, 0, stream>>>(h, att_src, att_dst, a_src, a_dst);
  k_out     <<<BB * (NN / 16), 256, 0, stream>>>(h, nbr, a_src, a_dst, bias, out);
}